// Round 1
// baseline (214.261 us; speedup 1.0000x reference)
//
#include <hip/hip_runtime.h>
#include <hip/hip_bf16.h>

typedef __bf16 bf16x8 __attribute__((ext_vector_type(8)));
typedef float  f32x4  __attribute__((ext_vector_type(4)));

#define N_IN   4096
#define N_OUT  1024
#define BATCH  16
#define ROWS   16

// LDS strides in __bf16 elements (padded for bank-conflict mitigation)
#define H1_STR   72     // 64 + 8
#define H2_STR   72
#define FT_JSTR  40     // 32 + 8  (filtT j-stride)
#define FT_NSTR  1288   // 32*40 + 8 (filtT n-stride)
#define G_STR    520    // 512 + 8
#define V_STR    520

__global__ void qc_zero_kernel(float* __restrict__ out, int n4) {
    int i = blockIdx.x * blockDim.x + threadIdx.x;
    if (i < n4) ((float4*)out)[i] = make_float4(0.f, 0.f, 0.f, 0.f);
}

// W3 (64,1024) fp32 -> W3T (1024,64) bf16 so phase-C B-fragments are contiguous b128 loads.
__global__ void qc_w3t_kernel(const float* __restrict__ w3, __bf16* __restrict__ w3t) {
    int gid = blockIdx.x * blockDim.x + threadIdx.x;   // 65536
    int k = gid & 63, col = gid >> 6;
    w3t[gid] = (__bf16)w3[k * 1024 + col];             // w3t[col*64+k]
}

__global__ __launch_bounds__(256, 2)
void qc_main_kernel(const float* __restrict__ feat,
                    const float* __restrict__ w1,
                    const float* __restrict__ w2,
                    const float* __restrict__ locs,
                    const int*   __restrict__ eidx,    // (E,2) int32: [seg, src]
                    const __bf16* __restrict__ w3t,
                    float* __restrict__ out,
                    int E)
{
    __shared__ __align__(16) __bf16 h1b[ROWS * H1_STR];          // 2304 B
    __shared__ __align__(16) __bf16 h2b[ROWS * H2_STR];          // 2304 B
    __shared__ __align__(16) __bf16 ftv[ROWS * FT_NSTR];         // 41216 B: filtT, later overlaid by vals
    __shared__ __align__(16) __bf16 gb [BATCH * G_STR];          // 16640 B
    __shared__ unsigned short seg_s[512];                        // 1024 B
    __shared__ unsigned short src_s[512];                        // 1024 B
    // total 64512 B <= 64KB -> 2 blocks/CU

    const int tid = threadIdx.x;
    const int n0  = blockIdx.x * ROWS;
    const int t0  = n0 * 32;
    const int ch0 = t0 / E;
    const int m0  = t0 - ch0 * E;          // m0 < E; block spans < 512 t's -> at most one wrap

    // ---------------- Phase A: h1 = sin(loc @ W1); stage seg/src ----------------
    {
        const int r  = tid >> 4;
        const int j0 = (tid & 15) * 4;
        float lx = 0.f, ly = 0.f;
        int n = n0 + r;
        if (n < E) { lx = locs[n * 2]; ly = locs[n * 2 + 1]; }
        float4 wa = *(const float4*)&w1[j0];
        float4 wb = *(const float4*)&w1[64 + j0];
        __bf16* h = &h1b[r * H1_STR + j0];
        h[0] = (__bf16)__sinf(lx * wa.x + ly * wb.x);
        h[1] = (__bf16)__sinf(lx * wa.y + ly * wb.y);
        h[2] = (__bf16)__sinf(lx * wa.z + ly * wb.z);
        h[3] = (__bf16)__sinf(lx * wa.w + ly * wb.w);
    }
    for (int tl = tid; tl < 512; tl += 256) {
        int mm = m0 + tl; if (mm >= E) mm -= E;
        seg_s[tl] = (unsigned short)eidx[mm * 2];      // seg < 1024
        src_s[tl] = (unsigned short)eidx[mm * 2 + 1];  // src < 4096
    }
    __syncthreads();

    // ---------------- Phase B: h2 = sin(h1 @ W2); gather features -> gb ----------------
    {
        const int r  = tid >> 4;
        const int j0 = (tid & 15) * 4;
        float a0 = 0.f, a1 = 0.f, a2 = 0.f, a3 = 0.f;
        const __bf16* h1r = &h1b[r * H1_STR];
        #pragma unroll 8
        for (int k = 0; k < 64; ++k) {
            float h = (float)h1r[k];
            float4 w = *(const float4*)&w2[k * 64 + j0];
            a0 += h * w.x; a1 += h * w.y; a2 += h * w.z; a3 += h * w.w;
        }
        __bf16* h = &h2b[r * H2_STR + j0];
        h[0] = (__bf16)__sinf(a0);
        h[1] = (__bf16)__sinf(a1);
        h[2] = (__bf16)__sinf(a2);
        h[3] = (__bf16)__sinf(a3);
    }
    #pragma unroll 4
    for (int it = 0; it < 32; ++it) {
        int idx = it * 256 + tid;          // 8192 = 16 b * 512 tloc
        int b   = idx >> 9;
        int tl  = idx & 511;
        int mm  = m0 + tl;
        int cc  = ch0 + (mm >= E);
        if (mm >= E) mm -= E;
        float v = 0.f;
        if (cc < 32) v = feat[(b * 32 + cc) * N_IN + (int)src_s[tl]];
        gb[b * G_STR + tl] = (__bf16)v;
    }
    __syncthreads();

    const int lane = tid & 63;
    const int wv   = tid >> 6;
    const int ml   = lane & 15;
    const int q    = lane >> 4;

    // ---------------- Phase C: filt = h2 @ W3 via MFMA; store as filtT[n][j][i] bf16 ----------------
    {
        // A: rows n (M=16), K=64. lane holds A[m=lane&15][k=quad*8+d]
        bf16x8 a0 = *(const bf16x8*)&h2b[ml * H2_STR + q * 8];
        bf16x8 a1 = *(const bf16x8*)&h2b[ml * H2_STR + 32 + q * 8];
        #pragma unroll
        for (int t = 0; t < 16; ++t) {
            int col = wv * 256 + t * 16 + ml;          // 0..1023 = i*32+j
            const __bf16* wp = &w3t[col * 64 + q * 8]; // B[k][col] contiguous in k
            bf16x8 b0 = *(const bf16x8*)wp;
            bf16x8 b1 = *(const bf16x8*)(wp + 32);
            f32x4 c = {0.f, 0.f, 0.f, 0.f};
            c = __builtin_amdgcn_mfma_f32_16x16x32_bf16(a0, b0, c, 0, 0, 0);
            c = __builtin_amdgcn_mfma_f32_16x16x32_bf16(a1, b1, c, 0, 0, 0);
            int i_ = col >> 5, j_ = col & 31;
            __bf16* fp = &ftv[j_ * FT_JSTR + i_];      // D row = n = quad*4+reg
            fp[(q * 4 + 0) * FT_NSTR] = (__bf16)c[0];
            fp[(q * 4 + 1) * FT_NSTR] = (__bf16)c[1];
            fp[(q * 4 + 2) * FT_NSTR] = (__bf16)c[2];
            fp[(q * 4 + 3) * FT_NSTR] = (__bf16)c[3];
        }
    }
    __syncthreads();

    // ---------------- Phase D: vals[b][j] = g[b][:] @ filt (per row), MFMA ----------------
    // Load all fragments first, barrier, then overlay vals onto the filtT LDS region.
    {
        bf16x8 ag[4], f0[4], f1[4];
        #pragma unroll
        for (int rr = 0; rr < 4; ++rr) {
            int r = wv * 4 + rr;
            ag[rr] = *(const bf16x8*)&gb[ml * G_STR + r * 32 + q * 8];
            f0[rr] = *(const bf16x8*)&ftv[r * FT_NSTR + ml        * FT_JSTR + q * 8];
            f1[rr] = *(const bf16x8*)&ftv[r * FT_NSTR + (16 + ml) * FT_JSTR + q * 8];
        }
        __syncthreads();   // all filtT reads done; ftv now becomes vals buffer
        __bf16* valsb = ftv;
        #pragma unroll
        for (int rr = 0; rr < 4; ++rr) {
            int r = wv * 4 + rr;
            f32x4 c0 = {0.f, 0.f, 0.f, 0.f};
            f32x4 c1 = {0.f, 0.f, 0.f, 0.f};
            c0 = __builtin_amdgcn_mfma_f32_16x16x32_bf16(ag[rr], f0[rr], c0, 0, 0, 0);
            c1 = __builtin_amdgcn_mfma_f32_16x16x32_bf16(ag[rr], f1[rr], c1, 0, 0, 0);
            __bf16* vp = &valsb[r * 32];
            #pragma unroll
            for (int g_ = 0; g_ < 4; ++g_) {
                int b = q * 4 + g_;                    // D row = batch
                vp[b * V_STR + ml]      = (__bf16)c0[g_];   // j = ml
                vp[b * V_STR + 16 + ml] = (__bf16)c1[g_];   // j = 16+ml
            }
        }
    }
    __syncthreads();

    // ---------------- Phase E: run-merged atomic scatter ----------------
    {
        const __bf16* valsb = ftv;
        const int b = tid >> 4;
        const int r = tid & 15;
        const __bf16* vp = &valsb[b * V_STR + r * 32];
        bf16x8 v0 = *(const bf16x8*)(vp);
        bf16x8 v1 = *(const bf16x8*)(vp + 8);
        bf16x8 v2 = *(const bf16x8*)(vp + 16);
        bf16x8 v3 = *(const bf16x8*)(vp + 24);
        float vv[32];
        #pragma unroll
        for (int j = 0; j < 8; ++j) {
            vv[j]      = (float)v0[j];
            vv[8 + j]  = (float)v1[j];
            vv[16 + j] = (float)v2[j];
            vv[24 + j] = (float)v3[j];
        }
        const int tl0 = r * 32;
        int key_prev = -1;
        float acc = 0.f;
        #pragma unroll
        for (int j = 0; j < 32; ++j) {
            int mm = m0 + tl0 + j;
            int cc = ch0 + (mm >= E);
            if (mm >= E) mm -= E;
            if (cc < 32) {
                int o   = (int)seg_s[tl0 + j];
                int key = ((b * 32 + cc) << 10) | o;   // flat index into out
                if (key != key_prev) {
                    if (key_prev >= 0) atomicAdd(&out[key_prev], acc);
                    key_prev = key;
                    acc = vv[j];
                } else {
                    acc += vv[j];
                }
            }
        }
        if (key_prev >= 0) atomicAdd(&out[key_prev], acc);
    }
}

extern "C" void kernel_launch(void* const* d_in, const int* in_sizes, int n_in,
                              void* d_out, int out_size, void* d_ws, size_t ws_size,
                              hipStream_t stream)
{
    (void)n_in; (void)ws_size;
    const float* feat = (const float*)d_in[0];
    const float* w1   = (const float*)d_in[1];
    const float* w2   = (const float*)d_in[2];
    const float* w3   = (const float*)d_in[3];
    const float* locs = (const float*)d_in[4];
    const int*   eidx = (const int*)d_in[5];   // harness delivers integer inputs as int32
    float* out  = (float*)d_out;
    __bf16* w3t = (__bf16*)d_ws;               // needs 128 KB of workspace

    const int E = in_sizes[4] / 2;             // eval_locs is (E,2) fp32
    if (E <= 0) return;

    int n4 = out_size / 4;                     // 524288 / 4
    qc_zero_kernel<<<(n4 + 255) / 256, 256, 0, stream>>>(out, n4);
    qc_w3t_kernel<<<256, 256, 0, stream>>>(w3, w3t);

    int nblocks = (E + ROWS - 1) / ROWS;
    qc_main_kernel<<<nblocks, 256, 0, stream>>>(feat, w1, w2, locs, eidx, w3t, out, E);
}

// Round 3
// 189.182 us; speedup vs baseline: 1.1326x; 1.1326x over previous
//
#include <hip/hip_runtime.h>
#include <hip/hip_bf16.h>

typedef __bf16 bf16x8 __attribute__((ext_vector_type(8)));
typedef float  f32x4  __attribute__((ext_vector_type(4)));

#define N_IN   4096
#define N_OUT  1024
#define BATCH  16
#define ROWS   16

// LDS strides in __bf16 elements (padded for bank-conflict mitigation)
#define H1_STR   72     // 64 + 8
#define H2_STR   72
#define FT_JSTR  40     // 32 + 8  (filtT j-stride)
#define FT_NSTR  1288   // 32*40 + 8 (filtT n-stride)
#define G_STR    520    // 512 + 8
#define V_STR    520

// ws layout: [0,131072) w3t bf16 (1024x64), [131072,139264) w2t bf16 (64x64),
//            [139264, ...) filt bf16, (E+16) rows x 1024, layout [n][j*32+i]
#define WS_W3T_OFF   0
#define WS_W2T_OFF   131072
#define WS_FILT_OFF  139264

__global__ void qc_zero_kernel(float* __restrict__ out, int n4) {
    int i = blockIdx.x * blockDim.x + threadIdx.x;
    if (i < n4) ((float4*)out)[i] = make_float4(0.f, 0.f, 0.f, 0.f);
}

// W3 (64,1024) fp32 -> w3t[col*64+k] bf16 ; W2 (64,64) fp32 -> w2t[col*64+k] bf16
__global__ void qc_prep_kernel(const float* __restrict__ w3, const float* __restrict__ w2,
                               __bf16* __restrict__ w3t, __bf16* __restrict__ w2t) {
    int gid = blockIdx.x * blockDim.x + threadIdx.x;   // 69632 threads
    if (gid < 65536) {
        int k = gid & 63, col = gid >> 6;
        w3t[gid] = (__bf16)w3[k * 1024 + col];
    } else {
        int j = gid - 65536;                           // < 4096
        int k = j & 63, col = j >> 6;
        w2t[j] = (__bf16)w2[k * 64 + col];
    }
}

// ---------------------------------------------------------------------------
// Kernel F: per 16-row tile compute h1 (VALU), h2 (MFMA vs w2t), filt (MFMA vs
// w3t), dump filtT[n][j*32+i] bf16 to global, coalesced.
// ---------------------------------------------------------------------------
__global__ __launch_bounds__(256, 3)
void qc_filt_kernel(const float* __restrict__ w1,
                    const float* __restrict__ locs,
                    const __bf16* __restrict__ w2t,
                    const __bf16* __restrict__ w3t,
                    __bf16* __restrict__ filt,
                    int E)
{
    __shared__ __align__(16) __bf16 h1b[ROWS * H1_STR];   // 2304 B
    __shared__ __align__(16) __bf16 h2b[ROWS * H2_STR];   // 2304 B
    __shared__ __align__(16) __bf16 ftv[ROWS * FT_NSTR];  // 41216 B
    // total ~45.8 KB -> 3 blocks/CU

    const int tid = threadIdx.x;
    const int n0  = blockIdx.x * ROWS;

    // Phase A: h1 = sin(loc @ W1)
    {
        const int r  = tid >> 4;
        const int j0 = (tid & 15) * 4;
        float lx = 0.f, ly = 0.f;
        int n = n0 + r;
        if (n < E) { lx = locs[n * 2]; ly = locs[n * 2 + 1]; }
        float4 wa = *(const float4*)&w1[j0];
        float4 wb = *(const float4*)&w1[64 + j0];
        __bf16* h = &h1b[r * H1_STR + j0];
        h[0] = (__bf16)__sinf(lx * wa.x + ly * wb.x);
        h[1] = (__bf16)__sinf(lx * wa.y + ly * wb.y);
        h[2] = (__bf16)__sinf(lx * wa.z + ly * wb.z);
        h[3] = (__bf16)__sinf(lx * wa.w + ly * wb.w);
    }
    __syncthreads();

    const int lane = tid & 63;
    const int wv   = tid >> 6;
    const int ml   = lane & 15;
    const int q    = lane >> 4;

    // Phase B: h2 = sin(h1 @ W2) via MFMA; wave wv owns cols [wv*16, wv*16+16)
    {
        bf16x8 a0 = *(const bf16x8*)&h1b[ml * H1_STR + q * 8];
        bf16x8 a1 = *(const bf16x8*)&h1b[ml * H1_STR + 32 + q * 8];
        const __bf16* wp = &w2t[(wv * 16 + ml) * 64 + q * 8];
        bf16x8 b0 = *(const bf16x8*)wp;
        bf16x8 b1 = *(const bf16x8*)(wp + 32);
        f32x4 c = {0.f, 0.f, 0.f, 0.f};
        c = __builtin_amdgcn_mfma_f32_16x16x32_bf16(a0, b0, c, 0, 0, 0);
        c = __builtin_amdgcn_mfma_f32_16x16x32_bf16(a1, b1, c, 0, 0, 0);
        #pragma unroll
        for (int g_ = 0; g_ < 4; ++g_)
            h2b[(q * 4 + g_) * H2_STR + wv * 16 + ml] = (__bf16)__sinf(c[g_]);
    }
    __syncthreads();

    // Phase C: filt = h2 @ W3 via MFMA; store filtT[n][j][i] into LDS
    {
        bf16x8 a0 = *(const bf16x8*)&h2b[ml * H2_STR + q * 8];
        bf16x8 a1 = *(const bf16x8*)&h2b[ml * H2_STR + 32 + q * 8];
        #pragma unroll
        for (int t = 0; t < 16; ++t) {
            int col = wv * 256 + t * 16 + ml;          // = i*32 + j
            const __bf16* wp = &w3t[col * 64 + q * 8];
            bf16x8 b0 = *(const bf16x8*)wp;
            bf16x8 b1 = *(const bf16x8*)(wp + 32);
            f32x4 c = {0.f, 0.f, 0.f, 0.f};
            c = __builtin_amdgcn_mfma_f32_16x16x32_bf16(a0, b0, c, 0, 0, 0);
            c = __builtin_amdgcn_mfma_f32_16x16x32_bf16(a1, b1, c, 0, 0, 0);
            int i_ = col >> 5, j_ = col & 31;
            __bf16* fp = &ftv[j_ * FT_JSTR + i_];
            fp[(q * 4 + 0) * FT_NSTR] = (__bf16)c[0];
            fp[(q * 4 + 1) * FT_NSTR] = (__bf16)c[1];
            fp[(q * 4 + 2) * FT_NSTR] = (__bf16)c[2];
            fp[(q * 4 + 3) * FT_NSTR] = (__bf16)c[3];
        }
    }
    __syncthreads();

    // Dump: filt[n0+n][c7*8 .. +8) = ftv[n][j*40 + i0]  (c7 = j*4 + i0/8)
    #pragma unroll
    for (int it = 0; it < 8; ++it) {
        int idx = it * 256 + tid;                      // 2048 chunks of 8
        int n   = idx >> 7;
        int c7  = idx & 127;
        int j_  = c7 >> 2;
        int i0  = (c7 & 3) * 8;
        if (n0 + n < E) {
            bf16x8 v = *(const bf16x8*)&ftv[n * FT_NSTR + j_ * FT_JSTR + i0];
            *(bf16x8*)&filt[(size_t)(n0 + n) * 1024 + c7 * 8] = v;
        }
    }
}

// ---------------------------------------------------------------------------
// Kernel G: gather features, einsum vs global filt (MFMA), run-merged scatter.
// ---------------------------------------------------------------------------
__global__ __launch_bounds__(256, 5)
void qc_scatter_kernel(const float* __restrict__ feat,
                       const int*   __restrict__ eidx,
                       const __bf16* __restrict__ filt,
                       float* __restrict__ out,
                       int E)
{
    __shared__ __align__(16) __bf16 gb[BATCH * G_STR];   // 16640 B (also vals)
    __shared__ unsigned short seg_s[512];
    __shared__ unsigned short src_s[512];
    // total ~18.7 KB

    const int tid = threadIdx.x;
    const int n0  = blockIdx.x * ROWS;
    const int t0  = n0 * 32;
    const int ch0 = t0 / E;
    const int m0  = t0 - ch0 * E;

    for (int tl = tid; tl < 512; tl += 256) {
        int mm = m0 + tl; if (mm >= E) mm -= E;
        seg_s[tl] = (unsigned short)eidx[mm * 2];
        src_s[tl] = (unsigned short)eidx[mm * 2 + 1];
    }
    __syncthreads();

    #pragma unroll 4
    for (int it = 0; it < 32; ++it) {
        int idx = it * 256 + tid;          // 8192 = 16 b * 512 tloc
        int b   = idx >> 9;
        int tl  = idx & 511;
        int mm  = m0 + tl;
        int cc  = ch0 + (mm >= E);
        if (mm >= E) mm -= E;
        float v = 0.f;
        if (cc < 32) v = feat[(b * 32 + cc) * N_IN + (int)src_s[tl]];
        gb[b * G_STR + tl] = (__bf16)v;
    }
    __syncthreads();

    const int lane = tid & 63;
    const int wv   = tid >> 6;
    const int ml   = lane & 15;
    const int q    = lane >> 4;

    // vals[b][j] = g[b][:] @ filt[r]  per row r, via MFMA; B-frags from global
    {
        bf16x8 ag[4], f0[4], f1[4];
        f32x4 c0[4], c1[4];
        #pragma unroll
        for (int rr = 0; rr < 4; ++rr) {
            int r = wv * 4 + rr;
            ag[rr] = *(const bf16x8*)&gb[ml * G_STR + r * 32 + q * 8];
            const __bf16* fp = &filt[(size_t)(n0 + r) * 1024 + ml * 32 + q * 8];
            f0[rr] = *(const bf16x8*)fp;          // j = ml
            f1[rr] = *(const bf16x8*)(fp + 512);  // j = 16 + ml
        }
        #pragma unroll
        for (int rr = 0; rr < 4; ++rr) {
            f32x4 z = {0.f, 0.f, 0.f, 0.f};
            c0[rr] = __builtin_amdgcn_mfma_f32_16x16x32_bf16(ag[rr], f0[rr], z, 0, 0, 0);
            c1[rr] = __builtin_amdgcn_mfma_f32_16x16x32_bf16(ag[rr], f1[rr], z, 0, 0, 0);
        }
        __syncthreads();   // gb reads complete; overlay vals onto gb
        __bf16* valsb = gb;
        #pragma unroll
        for (int rr = 0; rr < 4; ++rr) {
            int r = wv * 4 + rr;
            __bf16* vp = &valsb[r * 32];
            #pragma unroll
            for (int g_ = 0; g_ < 4; ++g_) {
                int b = q * 4 + g_;
                vp[b * V_STR + ml]      = (__bf16)c0[rr][g_];
                vp[b * V_STR + 16 + ml] = (__bf16)c1[rr][g_];
            }
        }
    }
    __syncthreads();

    // run-merged atomic scatter
    {
        const __bf16* valsb = gb;
        const int b = tid >> 4;
        const int r = tid & 15;
        const __bf16* vp = &valsb[b * V_STR + r * 32];
        bf16x8 v0 = *(const bf16x8*)(vp);
        bf16x8 v1 = *(const bf16x8*)(vp + 8);
        bf16x8 v2 = *(const bf16x8*)(vp + 16);
        bf16x8 v3 = *(const bf16x8*)(vp + 24);
        float vv[32];
        #pragma unroll
        for (int j = 0; j < 8; ++j) {
            vv[j]      = (float)v0[j];
            vv[8 + j]  = (float)v1[j];
            vv[16 + j] = (float)v2[j];
            vv[24 + j] = (float)v3[j];
        }
        const int tl0 = r * 32;
        int key_prev = -1;
        float acc = 0.f;
        #pragma unroll
        for (int j = 0; j < 32; ++j) {
            int mm = m0 + tl0 + j;
            int cc = ch0 + (mm >= E);
            if (mm >= E) mm -= E;
            if (cc < 32) {
                int o   = (int)seg_s[tl0 + j];
                int key = ((b * 32 + cc) << 10) | o;
                if (key != key_prev) {
                    if (key_prev >= 0) atomicAdd(&out[key_prev], acc);
                    key_prev = key;
                    acc = vv[j];
                } else {
                    acc += vv[j];
                }
            }
        }
        if (key_prev >= 0) atomicAdd(&out[key_prev], acc);
    }
}

// ---------------------------------------------------------------------------
// Fallback: the round-1 fused kernel (used only if ws too small for filt)
// ---------------------------------------------------------------------------
__global__ __launch_bounds__(256, 2)
void qc_main_kernel(const float* __restrict__ feat,
                    const float* __restrict__ w1,
                    const float* __restrict__ w2,
                    const float* __restrict__ locs,
                    const int*   __restrict__ eidx,
                    const __bf16* __restrict__ w3t,
                    float* __restrict__ out,
                    int E)
{
    __shared__ __align__(16) __bf16 h1b[ROWS * H1_STR];
    __shared__ __align__(16) __bf16 h2b[ROWS * H2_STR];
    __shared__ __align__(16) __bf16 ftv[ROWS * FT_NSTR];
    __shared__ __align__(16) __bf16 gb [BATCH * G_STR];
    __shared__ unsigned short seg_s[512];
    __shared__ unsigned short src_s[512];

    const int tid = threadIdx.x;
    const int n0  = blockIdx.x * ROWS;
    const int t0  = n0 * 32;
    const int ch0 = t0 / E;
    const int m0  = t0 - ch0 * E;

    {
        const int r  = tid >> 4;
        const int j0 = (tid & 15) * 4;
        float lx = 0.f, ly = 0.f;
        int n = n0 + r;
        if (n < E) { lx = locs[n * 2]; ly = locs[n * 2 + 1]; }
        float4 wa = *(const float4*)&w1[j0];
        float4 wb = *(const float4*)&w1[64 + j0];
        __bf16* h = &h1b[r * H1_STR + j0];
        h[0] = (__bf16)__sinf(lx * wa.x + ly * wb.x);
        h[1] = (__bf16)__sinf(lx * wa.y + ly * wb.y);
        h[2] = (__bf16)__sinf(lx * wa.z + ly * wb.z);
        h[3] = (__bf16)__sinf(lx * wa.w + ly * wb.w);
    }
    for (int tl = tid; tl < 512; tl += 256) {
        int mm = m0 + tl; if (mm >= E) mm -= E;
        seg_s[tl] = (unsigned short)eidx[mm * 2];
        src_s[tl] = (unsigned short)eidx[mm * 2 + 1];
    }
    __syncthreads();

    {
        const int r  = tid >> 4;
        const int j0 = (tid & 15) * 4;
        float a0 = 0.f, a1 = 0.f, a2 = 0.f, a3 = 0.f;
        const __bf16* h1r = &h1b[r * H1_STR];
        #pragma unroll 8
        for (int k = 0; k < 64; ++k) {
            float h = (float)h1r[k];
            float4 w = *(const float4*)&w2[k * 64 + j0];
            a0 += h * w.x; a1 += h * w.y; a2 += h * w.z; a3 += h * w.w;
        }
        __bf16* h = &h2b[r * H2_STR + j0];
        h[0] = (__bf16)__sinf(a0);
        h[1] = (__bf16)__sinf(a1);
        h[2] = (__bf16)__sinf(a2);
        h[3] = (__bf16)__sinf(a3);
    }
    #pragma unroll 4
    for (int it = 0; it < 32; ++it) {
        int idx = it * 256 + tid;
        int b   = idx >> 9;
        int tl  = idx & 511;
        int mm  = m0 + tl;
        int cc  = ch0 + (mm >= E);
        if (mm >= E) mm -= E;
        float v = 0.f;
        if (cc < 32) v = feat[(b * 32 + cc) * N_IN + (int)src_s[tl]];
        gb[b * G_STR + tl] = (__bf16)v;
    }
    __syncthreads();

    const int lane = tid & 63;
    const int wv   = tid >> 6;
    const int ml   = lane & 15;
    const int q    = lane >> 4;

    {
        bf16x8 a0 = *(const bf16x8*)&h2b[ml * H2_STR + q * 8];
        bf16x8 a1 = *(const bf16x8*)&h2b[ml * H2_STR + 32 + q * 8];
        #pragma unroll
        for (int t = 0; t < 16; ++t) {
            int col = wv * 256 + t * 16 + ml;
            const __bf16* wp = &w3t[col * 64 + q * 8];
            bf16x8 b0 = *(const bf16x8*)wp;
            bf16x8 b1 = *(const bf16x8*)(wp + 32);
            f32x4 c = {0.f, 0.f, 0.f, 0.f};
            c = __builtin_amdgcn_mfma_f32_16x16x32_bf16(a0, b0, c, 0, 0, 0);
            c = __builtin_amdgcn_mfma_f32_16x16x32_bf16(a1, b1, c, 0, 0, 0);
            int i_ = col >> 5, j_ = col & 31;
            __bf16* fp = &ftv[j_ * FT_JSTR + i_];
            fp[(q * 4 + 0) * FT_NSTR] = (__bf16)c[0];
            fp[(q * 4 + 1) * FT_NSTR] = (__bf16)c[1];
            fp[(q * 4 + 2) * FT_NSTR] = (__bf16)c[2];
            fp[(q * 4 + 3) * FT_NSTR] = (__bf16)c[3];
        }
    }
    __syncthreads();

    {
        bf16x8 ag[4], f0[4], f1[4];
        #pragma unroll
        for (int rr = 0; rr < 4; ++rr) {
            int r = wv * 4 + rr;
            ag[rr] = *(const bf16x8*)&gb[ml * G_STR + r * 32 + q * 8];
            f0[rr] = *(const bf16x8*)&ftv[r * FT_NSTR + ml        * FT_JSTR + q * 8];
            f1[rr] = *(const bf16x8*)&ftv[r * FT_NSTR + (16 + ml) * FT_JSTR + q * 8];
        }
        __syncthreads();
        __bf16* valsb = ftv;
        #pragma unroll
        for (int rr = 0; rr < 4; ++rr) {
            int r = wv * 4 + rr;
            f32x4 c0 = {0.f, 0.f, 0.f, 0.f};
            f32x4 c1 = {0.f, 0.f, 0.f, 0.f};
            c0 = __builtin_amdgcn_mfma_f32_16x16x32_bf16(ag[rr], f0[rr], c0, 0, 0, 0);
            c1 = __builtin_amdgcn_mfma_f32_16x16x32_bf16(ag[rr], f1[rr], c1, 0, 0, 0);
            __bf16* vp = &valsb[r * 32];
            #pragma unroll
            for (int g_ = 0; g_ < 4; ++g_) {
                int b = q * 4 + g_;
                vp[b * V_STR + ml]      = (__bf16)c0[g_];
                vp[b * V_STR + 16 + ml] = (__bf16)c1[g_];
            }
        }
    }
    __syncthreads();

    {
        const __bf16* valsb = ftv;
        const int b = tid >> 4;
        const int r = tid & 15;
        const __bf16* vp = &valsb[b * V_STR + r * 32];
        bf16x8 v0 = *(const bf16x8*)(vp);
        bf16x8 v1 = *(const bf16x8*)(vp + 8);
        bf16x8 v2 = *(const bf16x8*)(vp + 16);
        bf16x8 v3 = *(const bf16x8*)(vp + 24);
        float vv[32];
        #pragma unroll
        for (int j = 0; j < 8; ++j) {
            vv[j]      = (float)v0[j];
            vv[8 + j]  = (float)v1[j];
            vv[16 + j] = (float)v2[j];
            vv[24 + j] = (float)v3[j];
        }
        const int tl0 = r * 32;
        int key_prev = -1;
        float acc = 0.f;
        #pragma unroll
        for (int j = 0; j < 32; ++j) {
            int mm = m0 + tl0 + j;
            int cc = ch0 + (mm >= E);
            if (mm >= E) mm -= E;
            if (cc < 32) {
                int o   = (int)seg_s[tl0 + j];
                int key = ((b * 32 + cc) << 10) | o;
                if (key != key_prev) {
                    if (key_prev >= 0) atomicAdd(&out[key_prev], acc);
                    key_prev = key;
                    acc = vv[j];
                } else {
                    acc += vv[j];
                }
            }
        }
        if (key_prev >= 0) atomicAdd(&out[key_prev], acc);
    }
}

extern "C" void kernel_launch(void* const* d_in, const int* in_sizes, int n_in,
                              void* d_out, int out_size, void* d_ws, size_t ws_size,
                              hipStream_t stream)
{
    (void)n_in;
    const float* feat = (const float*)d_in[0];
    const float* w1   = (const float*)d_in[1];
    const float* w2   = (const float*)d_in[2];
    const float* w3   = (const float*)d_in[3];
    const float* locs = (const float*)d_in[4];
    const int*   eidx = (const int*)d_in[5];
    float* out  = (float*)d_out;

    const int E = in_sizes[4] / 2;
    if (E <= 0) return;

    __bf16* w3t  = (__bf16*)((char*)d_ws + WS_W3T_OFF);
    __bf16* w2t  = (__bf16*)((char*)d_ws + WS_W2T_OFF);
    __bf16* filt = (__bf16*)((char*)d_ws + WS_FILT_OFF);

    int n4 = out_size / 4;
    qc_zero_kernel<<<(n4 + 255) / 256, 256, 0, stream>>>(out, n4);
    qc_prep_kernel<<<272, 256, 0, stream>>>(w3, w2, w3t, w2t);

    int nblocks = (E + ROWS - 1) / ROWS;
    size_t need = (size_t)WS_FILT_OFF + (size_t)(nblocks * ROWS) * 1024 * sizeof(__bf16);

    if (ws_size >= need) {
        qc_filt_kernel<<<nblocks, 256, 0, stream>>>(w1, locs, w2t, w3t, filt, E);
        qc_scatter_kernel<<<nblocks, 256, 0, stream>>>(feat, eidx, filt, out, E);
    } else {
        qc_main_kernel<<<nblocks, 256, 0, stream>>>(feat, w1, w2, locs, eidx, w3t, out, E);
    }
}

// Round 4
// 172.430 us; speedup vs baseline: 1.2426x; 1.0972x over previous
//
#include <hip/hip_runtime.h>
#include <hip/hip_bf16.h>

typedef __bf16 bf16x8 __attribute__((ext_vector_type(8)));
typedef float  f32x4  __attribute__((ext_vector_type(4)));

#define N_IN   4096
#define N_OUT  1024
#define BATCH  16
#define ROWS   16

// LDS strides in __bf16 elements (padded for bank-conflict mitigation)
#define H1_STR   72     // 64 + 8
#define H2_STR   72
#define FT_JSTR  40     // 32 + 8  (filtT j-stride)
#define FT_NSTR  1288   // 32*40 + 8 (filtT n-stride)
#define G_STR    520    // 512 + 8
#define V_STR    520

// ws layout:
//   [0,131072)            w3t  bf16 (1024x64)
//   [131072,139264)       w2t  bf16 (64x64)
//   [139264,4333568)      featb bf16 (16*32*4096)
//   [4333568,...)         filt bf16, nblocks*16 rows x 1024, layout [n][j*32+i]
#define WS_W3T_OFF    0
#define WS_W2T_OFF    131072
#define WS_FEATB_OFF  139264
#define WS_FILT_OFF   4333568

__global__ void qc_zero_kernel(float* __restrict__ out, int n4) {
    int i = blockIdx.x * blockDim.x + threadIdx.x;
    if (i < n4) ((float4*)out)[i] = make_float4(0.f, 0.f, 0.f, 0.f);
}

// Fallback prep: W3 -> w3t only
__global__ void qc_prep_kernel(const float* __restrict__ w3, const float* __restrict__ w2,
                               __bf16* __restrict__ w3t, __bf16* __restrict__ w2t) {
    int gid = blockIdx.x * blockDim.x + threadIdx.x;
    if (gid < 65536) {
        int k = gid & 63, col = gid >> 6;
        w3t[gid] = (__bf16)w3[k * 1024 + col];
    } else {
        int j = gid - 65536;
        int k = j & 63, col = j >> 6;
        w2t[j] = (__bf16)w2[k * 64 + col];
    }
}

// Fused prep: zero out (512 blks) + w3t (256) + w2t (16) + featb (2048)
__global__ void qc_prep2_kernel(const float* __restrict__ w3, const float* __restrict__ w2,
                                const float* __restrict__ feat,
                                float* __restrict__ out,
                                __bf16* __restrict__ w3t, __bf16* __restrict__ w2t,
                                __bf16* __restrict__ featb) {
    int bid = blockIdx.x, tid = threadIdx.x;
    if (bid < 512) {
        int i = bid * 256 + tid;                     // 131072 float4s
        ((float4*)out)[i] = make_float4(0.f, 0.f, 0.f, 0.f);
    } else if (bid < 768) {
        int gid = (bid - 512) * 256 + tid;           // 65536
        int k = gid & 63, col = gid >> 6;
        w3t[gid] = (__bf16)w3[k * 1024 + col];
    } else if (bid < 784) {
        int j = (bid - 768) * 256 + tid;             // 4096
        int k = j & 63, col = j >> 6;
        w2t[j] = (__bf16)w2[k * 64 + col];
    } else {
        int i = (bid - 784) * 256 + tid;             // 524288 float4s of feat
        float4 f = ((const float4*)feat)[i];
        __bf16* p = &featb[i * 4];
        p[0] = (__bf16)f.x; p[1] = (__bf16)f.y; p[2] = (__bf16)f.z; p[3] = (__bf16)f.w;
    }
}

// ---------------------------------------------------------------------------
// Kernel F: 512 threads per 16-row tile. h1 (VALU) -> h2 (MFMA vs w2t) ->
// filt (MFMA vs w3t, 8 waves x 128 cols) -> coalesced dump filt[n][j*32+i].
// ---------------------------------------------------------------------------
__global__ __launch_bounds__(512, 6)
void qc_filt_kernel(const float* __restrict__ w1,
                    const float* __restrict__ locs,
                    const __bf16* __restrict__ w2t,
                    const __bf16* __restrict__ w3t,
                    __bf16* __restrict__ filt,
                    int E)
{
    __shared__ __align__(16) __bf16 h1b[ROWS * H1_STR];   // 2304 B
    __shared__ __align__(16) __bf16 h2b[ROWS * H2_STR];   // 2304 B
    __shared__ __align__(16) __bf16 ftv[ROWS * FT_NSTR];  // 41216 B
    // total ~45.8 KB -> 3 blocks/CU (24 waves, 75%)

    const int tid = threadIdx.x;
    const int n0  = blockIdx.x * ROWS;

    // Phase A: h1 = sin(loc @ W1); 16 rows x 64 cols, 2 cols/thread
    {
        const int r  = tid >> 5;
        const int j0 = (tid & 31) * 2;
        float lx = 0.f, ly = 0.f;
        int n = n0 + r;
        if (n < E) { lx = locs[n * 2]; ly = locs[n * 2 + 1]; }
        float2 wa = *(const float2*)&w1[j0];
        float2 wb = *(const float2*)&w1[64 + j0];
        __bf16* h = &h1b[r * H1_STR + j0];
        h[0] = (__bf16)__sinf(lx * wa.x + ly * wb.x);
        h[1] = (__bf16)__sinf(lx * wa.y + ly * wb.y);
    }
    __syncthreads();

    const int lane = tid & 63;
    const int wv   = tid >> 6;      // 0..7
    const int ml   = lane & 15;
    const int q    = lane >> 4;

    // Phase B: h2 = sin(h1 @ W2) via MFMA; waves 0..3 each do 16 cols
    if (wv < 4) {
        bf16x8 a0 = *(const bf16x8*)&h1b[ml * H1_STR + q * 8];
        bf16x8 a1 = *(const bf16x8*)&h1b[ml * H1_STR + 32 + q * 8];
        const __bf16* wp = &w2t[(wv * 16 + ml) * 64 + q * 8];
        bf16x8 b0 = *(const bf16x8*)wp;
        bf16x8 b1 = *(const bf16x8*)(wp + 32);
        f32x4 c = {0.f, 0.f, 0.f, 0.f};
        c = __builtin_amdgcn_mfma_f32_16x16x32_bf16(a0, b0, c, 0, 0, 0);
        c = __builtin_amdgcn_mfma_f32_16x16x32_bf16(a1, b1, c, 0, 0, 0);
        #pragma unroll
        for (int g_ = 0; g_ < 4; ++g_)
            h2b[(q * 4 + g_) * H2_STR + wv * 16 + ml] = (__bf16)__sinf(c[g_]);
    }
    __syncthreads();

    // Phase C: filt = h2 @ W3 via MFMA; wave wv owns cols [wv*128, wv*128+128)
    {
        bf16x8 a0 = *(const bf16x8*)&h2b[ml * H2_STR + q * 8];
        bf16x8 a1 = *(const bf16x8*)&h2b[ml * H2_STR + 32 + q * 8];
        #pragma unroll
        for (int t = 0; t < 8; ++t) {
            int col = wv * 128 + t * 16 + ml;          // = i*32 + j
            const __bf16* wp = &w3t[col * 64 + q * 8];
            bf16x8 b0 = *(const bf16x8*)wp;
            bf16x8 b1 = *(const bf16x8*)(wp + 32);
            f32x4 c = {0.f, 0.f, 0.f, 0.f};
            c = __builtin_amdgcn_mfma_f32_16x16x32_bf16(a0, b0, c, 0, 0, 0);
            c = __builtin_amdgcn_mfma_f32_16x16x32_bf16(a1, b1, c, 0, 0, 0);
            int i_ = col >> 5, j_ = col & 31;
            __bf16* fp = &ftv[j_ * FT_JSTR + i_];
            fp[(q * 4 + 0) * FT_NSTR] = (__bf16)c[0];
            fp[(q * 4 + 1) * FT_NSTR] = (__bf16)c[1];
            fp[(q * 4 + 2) * FT_NSTR] = (__bf16)c[2];
            fp[(q * 4 + 3) * FT_NSTR] = (__bf16)c[3];
        }
    }
    __syncthreads();

    // Dump: 2048 chunks of 8 bf16, 4 iters x 512 threads
    #pragma unroll
    for (int it = 0; it < 4; ++it) {
        int idx = it * 512 + tid;
        int n   = idx >> 7;
        int c7  = idx & 127;
        int j_  = c7 >> 2;
        int i0  = (c7 & 3) * 8;
        if (n0 + n < E) {
            bf16x8 v = *(const bf16x8*)&ftv[n * FT_NSTR + j_ * FT_JSTR + i0];
            *(bf16x8*)&filt[(size_t)(n0 + n) * 1024 + c7 * 8] = v;
        }
    }
}

// ---------------------------------------------------------------------------
// Kernel G: gather bf16 features (batched loads), einsum vs global filt
// (all fragments loaded before MFMAs), run-merged atomic scatter.
// ---------------------------------------------------------------------------
__global__ __launch_bounds__(256, 6)
void qc_scatter_kernel(const __bf16* __restrict__ featb,
                       const int*   __restrict__ eidx,
                       const __bf16* __restrict__ filt,
                       float* __restrict__ out,
                       int E)
{
    __shared__ __align__(16) __bf16 gb[BATCH * G_STR];   // 16640 B (also vals)
    __shared__ unsigned short seg_s[512];
    __shared__ unsigned short src_s[512];
    // total ~18.7 KB -> LDS allows 8 blocks; VGPR bound 6 -> 75% occ

    const int tid = threadIdx.x;
    const int n0  = blockIdx.x * ROWS;
    const int t0  = n0 * 32;
    const int ch0 = t0 / E;
    const int m0  = t0 - ch0 * E;

    for (int tl = tid; tl < 512; tl += 256) {
        int mm = m0 + tl; if (mm >= E) mm -= E;
        int2 p = ((const int2*)eidx)[mm];
        seg_s[tl] = (unsigned short)p.x;
        src_s[tl] = (unsigned short)p.y;
    }
    __syncthreads();

    // Gather: 2 batches of 16 unconditional loads -> 16 LDS writes
    #pragma unroll
    for (int half = 0; half < 2; ++half) {
        __bf16 vr[16];
        #pragma unroll
        for (int it = 0; it < 16; ++it) {
            int idx = (half * 16 + it) * 256 + tid;    // 8192 = 16 b * 512 tl
            int b   = idx >> 9;
            int tl  = idx & 511;
            int mm  = m0 + tl;
            int cc  = ch0 + (mm >= E);
            int ccc = cc < 32 ? cc : 31;               // clamp (tail block only)
            __bf16 v = featb[(b * 32 + ccc) * N_IN + (int)src_s[tl]];
            vr[it] = (cc < 32) ? v : (__bf16)0.f;
        }
        #pragma unroll
        for (int it = 0; it < 16; ++it) {
            int idx = (half * 16 + it) * 256 + tid;
            int b   = idx >> 9;
            int tl  = idx & 511;
            gb[b * G_STR + tl] = vr[it];
        }
    }
    __syncthreads();

    const int lane = tid & 63;
    const int wv   = tid >> 6;
    const int ml   = lane & 15;
    const int q    = lane >> 4;

    // vals[b][j] = g[b][:] @ filt[r] per row r via MFMA; batch ALL loads first
    {
        bf16x8 f0[4], f1[4];
        #pragma unroll
        for (int rr = 0; rr < 4; ++rr) {
            int r = wv * 4 + rr;
            const __bf16* fp = &filt[(size_t)(n0 + r) * 1024 + ml * 32 + q * 8];
            f0[rr] = *(const bf16x8*)fp;          // j = ml
            f1[rr] = *(const bf16x8*)(fp + 512);  // j = 16 + ml
        }
        bf16x8 ag[4];
        #pragma unroll
        for (int rr = 0; rr < 4; ++rr) {
            int r = wv * 4 + rr;
            ag[rr] = *(const bf16x8*)&gb[ml * G_STR + r * 32 + q * 8];
        }
        f32x4 c0[4], c1[4];
        #pragma unroll
        for (int rr = 0; rr < 4; ++rr) {
            f32x4 z = {0.f, 0.f, 0.f, 0.f};
            c0[rr] = __builtin_amdgcn_mfma_f32_16x16x32_bf16(ag[rr], f0[rr], z, 0, 0, 0);
            c1[rr] = __builtin_amdgcn_mfma_f32_16x16x32_bf16(ag[rr], f1[rr], z, 0, 0, 0);
        }
        __syncthreads();   // gb reads complete; overlay vals onto gb
        __bf16* valsb = gb;
        #pragma unroll
        for (int rr = 0; rr < 4; ++rr) {
            int r = wv * 4 + rr;
            __bf16* vp = &valsb[r * 32];
            #pragma unroll
            for (int g_ = 0; g_ < 4; ++g_) {
                int b = q * 4 + g_;
                vp[b * V_STR + ml]      = (__bf16)c0[rr][g_];
                vp[b * V_STR + 16 + ml] = (__bf16)c1[rr][g_];
            }
        }
    }
    __syncthreads();

    // run-merged atomic scatter
    {
        const __bf16* valsb = gb;
        const int b = tid >> 4;
        const int r = tid & 15;
        const __bf16* vp = &valsb[b * V_STR + r * 32];
        bf16x8 v0 = *(const bf16x8*)(vp);
        bf16x8 v1 = *(const bf16x8*)(vp + 8);
        bf16x8 v2 = *(const bf16x8*)(vp + 16);
        bf16x8 v3 = *(const bf16x8*)(vp + 24);
        float vv[32];
        #pragma unroll
        for (int j = 0; j < 8; ++j) {
            vv[j]      = (float)v0[j];
            vv[8 + j]  = (float)v1[j];
            vv[16 + j] = (float)v2[j];
            vv[24 + j] = (float)v3[j];
        }
        const int tl0 = r * 32;
        int key_prev = -1;
        float acc = 0.f;
        #pragma unroll
        for (int j = 0; j < 32; ++j) {
            int mm = m0 + tl0 + j;
            int cc = ch0 + (mm >= E);
            if (mm >= E) mm -= E;
            if (cc < 32) {
                int o   = (int)seg_s[tl0 + j];
                int key = ((b * 32 + cc) << 10) | o;
                if (key != key_prev) {
                    if (key_prev >= 0) atomicAdd(&out[key_prev], acc);
                    key_prev = key;
                    acc = vv[j];
                } else {
                    acc += vv[j];
                }
            }
        }
        if (key_prev >= 0) atomicAdd(&out[key_prev], acc);
    }
}

// ---------------------------------------------------------------------------
// Fallback: round-1 fused kernel (used only if ws too small)
// ---------------------------------------------------------------------------
__global__ __launch_bounds__(256, 2)
void qc_main_kernel(const float* __restrict__ feat,
                    const float* __restrict__ w1,
                    const float* __restrict__ w2,
                    const float* __restrict__ locs,
                    const int*   __restrict__ eidx,
                    const __bf16* __restrict__ w3t,
                    float* __restrict__ out,
                    int E)
{
    __shared__ __align__(16) __bf16 h1b[ROWS * H1_STR];
    __shared__ __align__(16) __bf16 h2b[ROWS * H2_STR];
    __shared__ __align__(16) __bf16 ftv[ROWS * FT_NSTR];
    __shared__ __align__(16) __bf16 gb [BATCH * G_STR];
    __shared__ unsigned short seg_s[512];
    __shared__ unsigned short src_s[512];

    const int tid = threadIdx.x;
    const int n0  = blockIdx.x * ROWS;
    const int t0  = n0 * 32;
    const int ch0 = t0 / E;
    const int m0  = t0 - ch0 * E;

    {
        const int r  = tid >> 4;
        const int j0 = (tid & 15) * 4;
        float lx = 0.f, ly = 0.f;
        int n = n0 + r;
        if (n < E) { lx = locs[n * 2]; ly = locs[n * 2 + 1]; }
        float4 wa = *(const float4*)&w1[j0];
        float4 wb = *(const float4*)&w1[64 + j0];
        __bf16* h = &h1b[r * H1_STR + j0];
        h[0] = (__bf16)__sinf(lx * wa.x + ly * wb.x);
        h[1] = (__bf16)__sinf(lx * wa.y + ly * wb.y);
        h[2] = (__bf16)__sinf(lx * wa.z + ly * wb.z);
        h[3] = (__bf16)__sinf(lx * wa.w + ly * wb.w);
    }
    for (int tl = tid; tl < 512; tl += 256) {
        int mm = m0 + tl; if (mm >= E) mm -= E;
        seg_s[tl] = (unsigned short)eidx[mm * 2];
        src_s[tl] = (unsigned short)eidx[mm * 2 + 1];
    }
    __syncthreads();

    {
        const int r  = tid >> 4;
        const int j0 = (tid & 15) * 4;
        float a0 = 0.f, a1 = 0.f, a2 = 0.f, a3 = 0.f;
        const __bf16* h1r = &h1b[r * H1_STR];
        #pragma unroll 8
        for (int k = 0; k < 64; ++k) {
            float h = (float)h1r[k];
            float4 w = *(const float4*)&w2[k * 64 + j0];
            a0 += h * w.x; a1 += h * w.y; a2 += h * w.z; a3 += h * w.w;
        }
        __bf16* h = &h2b[r * H2_STR + j0];
        h[0] = (__bf16)__sinf(a0);
        h[1] = (__bf16)__sinf(a1);
        h[2] = (__bf16)__sinf(a2);
        h[3] = (__bf16)__sinf(a3);
    }
    #pragma unroll 4
    for (int it = 0; it < 32; ++it) {
        int idx = it * 256 + tid;
        int b   = idx >> 9;
        int tl  = idx & 511;
        int mm  = m0 + tl;
        int cc  = ch0 + (mm >= E);
        if (mm >= E) mm -= E;
        float v = 0.f;
        if (cc < 32) v = feat[(b * 32 + cc) * N_IN + (int)src_s[tl]];
        gb[b * G_STR + tl] = (__bf16)v;
    }
    __syncthreads();

    const int lane = tid & 63;
    const int wv   = tid >> 6;
    const int ml   = lane & 15;
    const int q    = lane >> 4;

    {
        bf16x8 a0 = *(const bf16x8*)&h2b[ml * H2_STR + q * 8];
        bf16x8 a1 = *(const bf16x8*)&h2b[ml * H2_STR + 32 + q * 8];
        #pragma unroll
        for (int t = 0; t < 16; ++t) {
            int col = wv * 256 + t * 16 + ml;
            const __bf16* wp = &w3t[col * 64 + q * 8];
            bf16x8 b0 = *(const bf16x8*)wp;
            bf16x8 b1 = *(const bf16x8*)(wp + 32);
            f32x4 c = {0.f, 0.f, 0.f, 0.f};
            c = __builtin_amdgcn_mfma_f32_16x16x32_bf16(a0, b0, c, 0, 0, 0);
            c = __builtin_amdgcn_mfma_f32_16x16x32_bf16(a1, b1, c, 0, 0, 0);
            int i_ = col >> 5, j_ = col & 31;
            __bf16* fp = &ftv[j_ * FT_JSTR + i_];
            fp[(q * 4 + 0) * FT_NSTR] = (__bf16)c[0];
            fp[(q * 4 + 1) * FT_NSTR] = (__bf16)c[1];
            fp[(q * 4 + 2) * FT_NSTR] = (__bf16)c[2];
            fp[(q * 4 + 3) * FT_NSTR] = (__bf16)c[3];
        }
    }
    __syncthreads();

    {
        bf16x8 ag[4], f0[4], f1[4];
        #pragma unroll
        for (int rr = 0; rr < 4; ++rr) {
            int r = wv * 4 + rr;
            ag[rr] = *(const bf16x8*)&gb[ml * G_STR + r * 32 + q * 8];
            f0[rr] = *(const bf16x8*)&ftv[r * FT_NSTR + ml        * FT_JSTR + q * 8];
            f1[rr] = *(const bf16x8*)&ftv[r * FT_NSTR + (16 + ml) * FT_JSTR + q * 8];
        }
        __syncthreads();
        __bf16* valsb = ftv;
        #pragma unroll
        for (int rr = 0; rr < 4; ++rr) {
            int r = wv * 4 + rr;
            f32x4 c0 = {0.f, 0.f, 0.f, 0.f};
            f32x4 c1 = {0.f, 0.f, 0.f, 0.f};
            c0 = __builtin_amdgcn_mfma_f32_16x16x32_bf16(ag[rr], f0[rr], c0, 0, 0, 0);
            c1 = __builtin_amdgcn_mfma_f32_16x16x32_bf16(ag[rr], f1[rr], c1, 0, 0, 0);
            __bf16* vp = &valsb[r * 32];
            #pragma unroll
            for (int g_ = 0; g_ < 4; ++g_) {
                int b = q * 4 + g_;
                vp[b * V_STR + ml]      = (__bf16)c0[g_];
                vp[b * V_STR + 16 + ml] = (__bf16)c1[g_];
            }
        }
    }
    __syncthreads();

    {
        const __bf16* valsb = ftv;
        const int b = tid >> 4;
        const int r = tid & 15;
        const __bf16* vp = &valsb[b * V_STR + r * 32];
        bf16x8 v0 = *(const bf16x8*)(vp);
        bf16x8 v1 = *(const bf16x8*)(vp + 8);
        bf16x8 v2 = *(const bf16x8*)(vp + 16);
        bf16x8 v3 = *(const bf16x8*)(vp + 24);
        float vv[32];
        #pragma unroll
        for (int j = 0; j < 8; ++j) {
            vv[j]      = (float)v0[j];
            vv[8 + j]  = (float)v1[j];
            vv[16 + j] = (float)v2[j];
            vv[24 + j] = (float)v3[j];
        }
        const int tl0 = r * 32;
        int key_prev = -1;
        float acc = 0.f;
        #pragma unroll
        for (int j = 0; j < 32; ++j) {
            int mm = m0 + tl0 + j;
            int cc = ch0 + (mm >= E);
            if (mm >= E) mm -= E;
            if (cc < 32) {
                int o   = (int)seg_s[tl0 + j];
                int key = ((b * 32 + cc) << 10) | o;
                if (key != key_prev) {
                    if (key_prev >= 0) atomicAdd(&out[key_prev], acc);
                    key_prev = key;
                    acc = vv[j];
                } else {
                    acc += vv[j];
                }
            }
        }
        if (key_prev >= 0) atomicAdd(&out[key_prev], acc);
    }
}

extern "C" void kernel_launch(void* const* d_in, const int* in_sizes, int n_in,
                              void* d_out, int out_size, void* d_ws, size_t ws_size,
                              hipStream_t stream)
{
    (void)n_in;
    const float* feat = (const float*)d_in[0];
    const float* w1   = (const float*)d_in[1];
    const float* w2   = (const float*)d_in[2];
    const float* w3   = (const float*)d_in[3];
    const float* locs = (const float*)d_in[4];
    const int*   eidx = (const int*)d_in[5];
    float* out  = (float*)d_out;

    const int E = in_sizes[4] / 2;
    if (E <= 0) return;

    __bf16* w3t   = (__bf16*)((char*)d_ws + WS_W3T_OFF);
    __bf16* w2t   = (__bf16*)((char*)d_ws + WS_W2T_OFF);
    __bf16* featb = (__bf16*)((char*)d_ws + WS_FEATB_OFF);
    __bf16* filt  = (__bf16*)((char*)d_ws + WS_FILT_OFF);

    int nblocks = (E + ROWS - 1) / ROWS;
    size_t need = (size_t)WS_FILT_OFF + (size_t)(nblocks * ROWS) * 1024 * sizeof(__bf16);

    if (ws_size >= need) {
        qc_prep2_kernel<<<2832, 256, 0, stream>>>(w3, w2, feat, out, w3t, w2t, featb);
        qc_filt_kernel<<<nblocks, 512, 0, stream>>>(w1, locs, w2t, w3t, filt, E);
        qc_scatter_kernel<<<nblocks, 256, 0, stream>>>(featb, eidx, filt, out, E);
    } else {
        int n4 = out_size / 4;
        qc_zero_kernel<<<(n4 + 255) / 256, 256, 0, stream>>>(out, n4);
        qc_prep_kernel<<<272, 256, 0, stream>>>(w3, w2, w3t, w2t);
        qc_main_kernel<<<nblocks, 256, 0, stream>>>(feat, w1, w2, locs, eidx, w3t, out, E);
    }
}

// Round 5
// 169.614 us; speedup vs baseline: 1.2632x; 1.0166x over previous
//
#include <hip/hip_runtime.h>
#include <hip/hip_bf16.h>

typedef __bf16 bf16x8 __attribute__((ext_vector_type(8)));
typedef float  f32x4  __attribute__((ext_vector_type(4)));

#define N_IN   4096
#define N_OUT  1024
#define BATCH  16
#define ROWS   16

// LDS strides in __bf16 elements
#define H1_STR   72     // 64 + 8
#define H2_STR   72
#define FT_JSTR  40     // 32 + 8  (filtT j-stride; 8-way b16 write aliasing, aligned b128 reads)
#define FT_NSTR  1280   // 32*40   (filtT n-stride)
#define G_STR    520    // 512 + 8
#define V_STR    520

// ws layout:
//   [0,131072)       w3t  bf16 (1024x64)
//   [131072,139264)  w2t  bf16 (64x64)
//   [139264,4333568) featb bf16 (16*32*4096)
#define WS_W3T_OFF    0
#define WS_W2T_OFF    131072
#define WS_FEATB_OFF  139264
#define WS_NEED       4333568

__global__ void qc_zero_kernel(float* __restrict__ out, int n4) {
    int i = blockIdx.x * blockDim.x + threadIdx.x;
    if (i < n4) ((float4*)out)[i] = make_float4(0.f, 0.f, 0.f, 0.f);
}

// Fallback prep: w3t/w2t only
__global__ void qc_prep_kernel(const float* __restrict__ w3, const float* __restrict__ w2,
                               __bf16* __restrict__ w3t, __bf16* __restrict__ w2t) {
    int gid = blockIdx.x * blockDim.x + threadIdx.x;
    if (gid < 65536) {
        int k = gid & 63, col = gid >> 6;
        w3t[gid] = (__bf16)w3[k * 1024 + col];
    } else {
        int j = gid - 65536;
        int k = j & 63, col = j >> 6;
        w2t[j] = (__bf16)w2[k * 64 + col];
    }
}

// Fused prep: zero out (512 blks) + w3t (256) + w2t (16) + featb (2048)
__global__ void qc_prep2_kernel(const float* __restrict__ w3, const float* __restrict__ w2,
                                const float* __restrict__ feat,
                                float* __restrict__ out,
                                __bf16* __restrict__ w3t, __bf16* __restrict__ w2t,
                                __bf16* __restrict__ featb) {
    int bid = blockIdx.x, tid = threadIdx.x;
    if (bid < 512) {
        int i = bid * 256 + tid;                     // 131072 float4s
        ((float4*)out)[i] = make_float4(0.f, 0.f, 0.f, 0.f);
    } else if (bid < 768) {
        int gid = (bid - 512) * 256 + tid;           // 65536
        int k = gid & 63, col = gid >> 6;
        w3t[gid] = (__bf16)w3[k * 1024 + col];
    } else if (bid < 784) {
        int j = (bid - 768) * 256 + tid;             // 4096
        int k = j & 63, col = j >> 6;
        w2t[j] = (__bf16)w2[k * 64 + col];
    } else {
        int i = (bid - 784) * 256 + tid;             // 524288 float4s of feat
        float4 f = ((const float4*)feat)[i];
        __bf16* p = &featb[i * 4];
        p[0] = (__bf16)f.x; p[1] = (__bf16)f.y; p[2] = (__bf16)f.z; p[3] = (__bf16)f.w;
    }
}

// ---------------------------------------------------------------------------
// Fused kernel: 512 threads per 16-row tile.
//   idx+h1 -> S1 -> [issue 16 gather loads] -> h2 (MFMA) -> S2 ->
//   filt (MFMA, LDS) + gather->gb -> S3 -> einsum (MFMA) -> vals -> scatter.
// filtT never leaves LDS (kills the 93MB+80MB HBM round-trip of the split).
// ---------------------------------------------------------------------------
__global__ __launch_bounds__(512, 4)
void qc_fused_kernel(const __bf16* __restrict__ featb,
                     const float* __restrict__ w1,
                     const float* __restrict__ locs,
                     const int*   __restrict__ eidx,
                     const __bf16* __restrict__ w2t,
                     const __bf16* __restrict__ w3t,
                     float* __restrict__ out,
                     int E)
{
    __shared__ __align__(16) __bf16 h1b[ROWS * H1_STR];   // 2304 B
    __shared__ __align__(16) __bf16 h2b[ROWS * H2_STR];   // 2304 B
    __shared__ __align__(16) __bf16 ftv[ROWS * FT_NSTR];  // 40960 B
    __shared__ __align__(16) __bf16 gb [BATCH * G_STR];   // 16640 B (later: vals)
    __shared__ unsigned short seg_s[512];                 // 1024 B
    __shared__ unsigned short src_s[512];                 // 1024 B
    // total 64256 B -> 2 blocks/CU (16 waves, 50%)

    const int tid = threadIdx.x;
    const int n0  = blockIdx.x * ROWS;
    const int t0  = n0 * 32;
    const int ch0 = t0 / E;
    const int m0  = t0 - ch0 * E;          // block spans <512 t's -> at most one wrap

    // ---- idx stage (1 per thread) + Phase A: h1 = sin(loc @ W1) ----
    {
        int mm = m0 + tid; if (mm >= E) mm -= E;
        int2 p = ((const int2*)eidx)[mm];
        seg_s[tid] = (unsigned short)p.x;
        src_s[tid] = (unsigned short)p.y;
    }
    {
        const int r  = tid >> 5;
        const int j0 = (tid & 31) * 2;
        float lx = 0.f, ly = 0.f;
        int n = n0 + r;
        if (n < E) { lx = locs[n * 2]; ly = locs[n * 2 + 1]; }
        float2 wa = *(const float2*)&w1[j0];
        float2 wb = *(const float2*)&w1[64 + j0];
        __bf16* h = &h1b[r * H1_STR + j0];
        h[0] = (__bf16)__sinf(lx * wa.x + ly * wb.x);
        h[1] = (__bf16)__sinf(lx * wa.y + ly * wb.y);
    }
    __syncthreads();   // S1

    // ---- Gather: issue 16 independent loads NOW (drain hidden by B+C) ----
    // With 512 threads: batch b = it, tl = tid.
    __bf16 vr[16];
    {
        int mm  = m0 + tid;
        int cc  = ch0 + (mm >= E);
        int ccc = cc < 32 ? cc : 31;                  // clamp (tail only)
        const __bf16* fp = &featb[ccc * N_IN + (int)src_s[tid]];
        #pragma unroll
        for (int it = 0; it < 16; ++it)
            vr[it] = fp[it * (32 * N_IN)];
        if (cc >= 32) {
            #pragma unroll
            for (int it = 0; it < 16; ++it) vr[it] = (__bf16)0.f;
        }
    }

    const int lane = tid & 63;
    const int wv   = tid >> 6;      // 0..7
    const int ml   = lane & 15;
    const int q    = lane >> 4;

    // ---- Phase B: h2 = sin(h1 @ W2) via MFMA (waves 0..3, 16 cols each) ----
    if (wv < 4) {
        bf16x8 a0 = *(const bf16x8*)&h1b[ml * H1_STR + q * 8];
        bf16x8 a1 = *(const bf16x8*)&h1b[ml * H1_STR + 32 + q * 8];
        const __bf16* wp = &w2t[(wv * 16 + ml) * 64 + q * 8];
        bf16x8 b0 = *(const bf16x8*)wp;
        bf16x8 b1 = *(const bf16x8*)(wp + 32);
        f32x4 c = {0.f, 0.f, 0.f, 0.f};
        c = __builtin_amdgcn_mfma_f32_16x16x32_bf16(a0, b0, c, 0, 0, 0);
        c = __builtin_amdgcn_mfma_f32_16x16x32_bf16(a1, b1, c, 0, 0, 0);
        #pragma unroll
        for (int g_ = 0; g_ < 4; ++g_)
            h2b[(q * 4 + g_) * H2_STR + wv * 16 + ml] = (__bf16)__sinf(c[g_]);
    }
    __syncthreads();   // S2

    // ---- Phase C: filt = h2 @ W3 via MFMA; filtT[n][j][i] into LDS ----
    {
        bf16x8 a0 = *(const bf16x8*)&h2b[ml * H2_STR + q * 8];
        bf16x8 a1 = *(const bf16x8*)&h2b[ml * H2_STR + 32 + q * 8];
        #pragma unroll
        for (int t = 0; t < 8; ++t) {
            int col = wv * 128 + t * 16 + ml;          // = i*32 + j
            const __bf16* wp = &w3t[col * 64 + q * 8];
            bf16x8 b0 = *(const bf16x8*)wp;
            bf16x8 b1 = *(const bf16x8*)(wp + 32);
            f32x4 c = {0.f, 0.f, 0.f, 0.f};
            c = __builtin_amdgcn_mfma_f32_16x16x32_bf16(a0, b0, c, 0, 0, 0);
            c = __builtin_amdgcn_mfma_f32_16x16x32_bf16(a1, b1, c, 0, 0, 0);
            int i_ = col >> 5, j_ = col & 31;
            __bf16* fp = &ftv[j_ * FT_JSTR + i_];
            fp[(q * 4 + 0) * FT_NSTR] = (__bf16)c[0];
            fp[(q * 4 + 1) * FT_NSTR] = (__bf16)c[1];
            fp[(q * 4 + 2) * FT_NSTR] = (__bf16)c[2];
            fp[(q * 4 + 3) * FT_NSTR] = (__bf16)c[3];
        }
    }
    // ---- Park gathered features into gb (loads have had B+C to drain) ----
    #pragma unroll
    for (int it = 0; it < 16; ++it)
        gb[it * G_STR + tid] = vr[it];
    __syncthreads();   // S3

    // ---- Phase D: vals[b][j] = g[b][:] @ filt[r]; 8 waves x 2 rows ----
    {
        bf16x8 ag[2], f0[2], f1[2];
        #pragma unroll
        for (int rr = 0; rr < 2; ++rr) {
            int r = wv * 2 + rr;
            f0[rr] = *(const bf16x8*)&ftv[r * FT_NSTR + ml        * FT_JSTR + q * 8];
            f1[rr] = *(const bf16x8*)&ftv[r * FT_NSTR + (16 + ml) * FT_JSTR + q * 8];
            ag[rr] = *(const bf16x8*)&gb[ml * G_STR + r * 32 + q * 8];
        }
        f32x4 c0[2], c1[2];
        #pragma unroll
        for (int rr = 0; rr < 2; ++rr) {
            f32x4 z = {0.f, 0.f, 0.f, 0.f};
            c0[rr] = __builtin_amdgcn_mfma_f32_16x16x32_bf16(ag[rr], f0[rr], z, 0, 0, 0);
            c1[rr] = __builtin_amdgcn_mfma_f32_16x16x32_bf16(ag[rr], f1[rr], z, 0, 0, 0);
        }
        __syncthreads();   // S4a: gb reads done; overlay vals onto gb
        __bf16* valsb = gb;
        #pragma unroll
        for (int rr = 0; rr < 2; ++rr) {
            int r = wv * 2 + rr;
            __bf16* vp = &valsb[r * 32];
            #pragma unroll
            for (int g_ = 0; g_ < 4; ++g_) {
                int b = q * 4 + g_;
                vp[b * V_STR + ml]      = (__bf16)c0[rr][g_];
                vp[b * V_STR + 16 + ml] = (__bf16)c1[rr][g_];
            }
        }
    }
    __syncthreads();   // S4b

    // ---- Phase E: run-merged atomic scatter (512 thr x 16 vals) ----
    {
        const __bf16* valsb = gb;
        const int b    = tid >> 5;            // 0..15
        const int rem  = tid & 31;
        const int tl0  = (rem >> 1) * 32 + (rem & 1) * 16;
        const __bf16* vp = &valsb[b * V_STR + tl0];
        bf16x8 v0 = *(const bf16x8*)(vp);
        bf16x8 v1 = *(const bf16x8*)(vp + 8);
        float vv[16];
        #pragma unroll
        for (int j = 0; j < 8; ++j) { vv[j] = (float)v0[j]; vv[8 + j] = (float)v1[j]; }
        int key_prev = -1;
        float acc = 0.f;
        #pragma unroll
        for (int j = 0; j < 16; ++j) {
            int mm = m0 + tl0 + j;
            int cc = ch0 + (mm >= E);
            if (mm >= E) mm -= E;
            if (cc < 32) {
                int o   = (int)seg_s[tl0 + j];
                int key = ((b * 32 + cc) << 10) | o;
                if (key != key_prev) {
                    if (key_prev >= 0) atomicAdd(&out[key_prev], acc);
                    key_prev = key;
                    acc = vv[j];
                } else {
                    acc += vv[j];
                }
            }
        }
        if (key_prev >= 0) atomicAdd(&out[key_prev], acc);
    }
}

// ---------------------------------------------------------------------------
// Fallback: round-1 fused kernel (used only if ws too small)
// ---------------------------------------------------------------------------
#define FB_FT_NSTR 1288
__global__ __launch_bounds__(256, 2)
void qc_main_kernel(const float* __restrict__ feat,
                    const float* __restrict__ w1,
                    const float* __restrict__ w2,
                    const float* __restrict__ locs,
                    const int*   __restrict__ eidx,
                    const __bf16* __restrict__ w3t,
                    float* __restrict__ out,
                    int E)
{
    __shared__ __align__(16) __bf16 h1b[ROWS * H1_STR];
    __shared__ __align__(16) __bf16 h2b[ROWS * H2_STR];
    __shared__ __align__(16) __bf16 ftv[ROWS * FB_FT_NSTR];
    __shared__ __align__(16) __bf16 gb [BATCH * G_STR];
    __shared__ unsigned short seg_s[512];
    __shared__ unsigned short src_s[512];

    const int tid = threadIdx.x;
    const int n0  = blockIdx.x * ROWS;
    const int t0  = n0 * 32;
    const int ch0 = t0 / E;
    const int m0  = t0 - ch0 * E;

    {
        const int r  = tid >> 4;
        const int j0 = (tid & 15) * 4;
        float lx = 0.f, ly = 0.f;
        int n = n0 + r;
        if (n < E) { lx = locs[n * 2]; ly = locs[n * 2 + 1]; }
        float4 wa = *(const float4*)&w1[j0];
        float4 wb = *(const float4*)&w1[64 + j0];
        __bf16* h = &h1b[r * H1_STR + j0];
        h[0] = (__bf16)__sinf(lx * wa.x + ly * wb.x);
        h[1] = (__bf16)__sinf(lx * wa.y + ly * wb.y);
        h[2] = (__bf16)__sinf(lx * wa.z + ly * wb.z);
        h[3] = (__bf16)__sinf(lx * wa.w + ly * wb.w);
    }
    for (int tl = tid; tl < 512; tl += 256) {
        int mm = m0 + tl; if (mm >= E) mm -= E;
        seg_s[tl] = (unsigned short)eidx[mm * 2];
        src_s[tl] = (unsigned short)eidx[mm * 2 + 1];
    }
    __syncthreads();

    {
        const int r  = tid >> 4;
        const int j0 = (tid & 15) * 4;
        float a0 = 0.f, a1 = 0.f, a2 = 0.f, a3 = 0.f;
        const __bf16* h1r = &h1b[r * H1_STR];
        #pragma unroll 8
        for (int k = 0; k < 64; ++k) {
            float h = (float)h1r[k];
            float4 w = *(const float4*)&w2[k * 64 + j0];
            a0 += h * w.x; a1 += h * w.y; a2 += h * w.z; a3 += h * w.w;
        }
        __bf16* h = &h2b[r * H2_STR + j0];
        h[0] = (__bf16)__sinf(a0);
        h[1] = (__bf16)__sinf(a1);
        h[2] = (__bf16)__sinf(a2);
        h[3] = (__bf16)__sinf(a3);
    }
    #pragma unroll 4
    for (int it = 0; it < 32; ++it) {
        int idx = it * 256 + tid;
        int b   = idx >> 9;
        int tl  = idx & 511;
        int mm  = m0 + tl;
        int cc  = ch0 + (mm >= E);
        if (mm >= E) mm -= E;
        float v = 0.f;
        if (cc < 32) v = feat[(b * 32 + cc) * N_IN + (int)src_s[tl]];
        gb[b * G_STR + tl] = (__bf16)v;
    }
    __syncthreads();

    const int lane = tid & 63;
    const int wv   = tid >> 6;
    const int ml   = lane & 15;
    const int q    = lane >> 4;

    {
        bf16x8 a0 = *(const bf16x8*)&h2b[ml * H2_STR + q * 8];
        bf16x8 a1 = *(const bf16x8*)&h2b[ml * H2_STR + 32 + q * 8];
        #pragma unroll
        for (int t = 0; t < 16; ++t) {
            int col = wv * 256 + t * 16 + ml;
            const __bf16* wp = &w3t[col * 64 + q * 8];
            bf16x8 b0 = *(const bf16x8*)wp;
            bf16x8 b1 = *(const bf16x8*)(wp + 32);
            f32x4 c = {0.f, 0.f, 0.f, 0.f};
            c = __builtin_amdgcn_mfma_f32_16x16x32_bf16(a0, b0, c, 0, 0, 0);
            c = __builtin_amdgcn_mfma_f32_16x16x32_bf16(a1, b1, c, 0, 0, 0);
            int i_ = col >> 5, j_ = col & 31;
            __bf16* fp = &ftv[j_ * FT_JSTR + i_];
            fp[(q * 4 + 0) * FB_FT_NSTR] = (__bf16)c[0];
            fp[(q * 4 + 1) * FB_FT_NSTR] = (__bf16)c[1];
            fp[(q * 4 + 2) * FB_FT_NSTR] = (__bf16)c[2];
            fp[(q * 4 + 3) * FB_FT_NSTR] = (__bf16)c[3];
        }
    }
    __syncthreads();

    {
        bf16x8 ag[4], f0[4], f1[4];
        #pragma unroll
        for (int rr = 0; rr < 4; ++rr) {
            int r = wv * 4 + rr;
            ag[rr] = *(const bf16x8*)&gb[ml * G_STR + r * 32 + q * 8];
            f0[rr] = *(const bf16x8*)&ftv[r * FB_FT_NSTR + ml        * FT_JSTR + q * 8];
            f1[rr] = *(const bf16x8*)&ftv[r * FB_FT_NSTR + (16 + ml) * FT_JSTR + q * 8];
        }
        __syncthreads();
        __bf16* valsb = ftv;
        #pragma unroll
        for (int rr = 0; rr < 4; ++rr) {
            int r = wv * 4 + rr;
            f32x4 c0 = {0.f, 0.f, 0.f, 0.f};
            f32x4 c1 = {0.f, 0.f, 0.f, 0.f};
            c0 = __builtin_amdgcn_mfma_f32_16x16x32_bf16(ag[rr], f0[rr], c0, 0, 0, 0);
            c1 = __builtin_amdgcn_mfma_f32_16x16x32_bf16(ag[rr], f1[rr], c1, 0, 0, 0);
            __bf16* vp = &valsb[r * 32];
            #pragma unroll
            for (int g_ = 0; g_ < 4; ++g_) {
                int b = q * 4 + g_;
                vp[b * V_STR + ml]      = (__bf16)c0[g_];
                vp[b * V_STR + 16 + ml] = (__bf16)c1[g_];
            }
        }
    }
    __syncthreads();

    {
        const __bf16* valsb = ftv;
        const int b = tid >> 4;
        const int r = tid & 15;
        const __bf16* vp = &valsb[b * V_STR + r * 32];
        bf16x8 v0 = *(const bf16x8*)(vp);
        bf16x8 v1 = *(const bf16x8*)(vp + 8);
        bf16x8 v2 = *(const bf16x8*)(vp + 16);
        bf16x8 v3 = *(const bf16x8*)(vp + 24);
        float vv[32];
        #pragma unroll
        for (int j = 0; j < 8; ++j) {
            vv[j]      = (float)v0[j];
            vv[8 + j]  = (float)v1[j];
            vv[16 + j] = (float)v2[j];
            vv[24 + j] = (float)v3[j];
        }
        const int tl0 = r * 32;
        int key_prev = -1;
        float acc = 0.f;
        #pragma unroll
        for (int j = 0; j < 32; ++j) {
            int mm = m0 + tl0 + j;
            int cc = ch0 + (mm >= E);
            if (mm >= E) mm -= E;
            if (cc < 32) {
                int o   = (int)seg_s[tl0 + j];
                int key = ((b * 32 + cc) << 10) | o;
                if (key != key_prev) {
                    if (key_prev >= 0) atomicAdd(&out[key_prev], acc);
                    key_prev = key;
                    acc = vv[j];
                } else {
                    acc += vv[j];
                }
            }
        }
        if (key_prev >= 0) atomicAdd(&out[key_prev], acc);
    }
}

extern "C" void kernel_launch(void* const* d_in, const int* in_sizes, int n_in,
                              void* d_out, int out_size, void* d_ws, size_t ws_size,
                              hipStream_t stream)
{
    (void)n_in;
    const float* feat = (const float*)d_in[0];
    const float* w1   = (const float*)d_in[1];
    const float* w2   = (const float*)d_in[2];
    const float* w3   = (const float*)d_in[3];
    const float* locs = (const float*)d_in[4];
    const int*   eidx = (const int*)d_in[5];
    float* out  = (float*)d_out;

    const int E = in_sizes[4] / 2;
    if (E <= 0) return;

    __bf16* w3t   = (__bf16*)((char*)d_ws + WS_W3T_OFF);
    __bf16* w2t   = (__bf16*)((char*)d_ws + WS_W2T_OFF);
    __bf16* featb = (__bf16*)((char*)d_ws + WS_FEATB_OFF);

    int nblocks = (E + ROWS - 1) / ROWS;

    if (ws_size >= (size_t)WS_NEED) {
        qc_prep2_kernel<<<2832, 256, 0, stream>>>(w3, w2, feat, out, w3t, w2t, featb);
        qc_fused_kernel<<<nblocks, 512, 0, stream>>>(featb, w1, locs, eidx, w2t, w3t, out, E);
    } else {
        int n4 = out_size / 4;
        qc_zero_kernel<<<(n4 + 255) / 256, 256, 0, stream>>>(out, n4);
        qc_prep_kernel<<<272, 256, 0, stream>>>(w3, w2, w3t, w2t);
        qc_main_kernel<<<nblocks, 256, 0, stream>>>(feat, w1, w2, locs, eidx, w3t, out, E);
    }
}

// Round 6
// 157.151 us; speedup vs baseline: 1.3634x; 1.0793x over previous
//
#include <hip/hip_runtime.h>
#include <hip/hip_bf16.h>

typedef __bf16 bf16x8  __attribute__((ext_vector_type(8)));
typedef __bf16 bf16x16 __attribute__((ext_vector_type(16)));
typedef float  f32x4   __attribute__((ext_vector_type(4)));

#define N_IN   4096
#define N_OUT  1024
#define BATCH  16
#define ROWS   16

// LDS strides in __bf16 elements
#define H1_STR   72     // 64 + 8
#define H2_STR   72
#define FT_JSTR  40     // 32 + 8  (filtT j-stride)
#define FT_NSTR  1280   // 32*40   (filtT n-stride)
#define G_STR    520    // 512 + 8
#define V_STR    520

// ws layout:
//   [0,131072)       w3t  bf16 (1024x64)       w3t[col*64+k]
//   [131072,139264)  w2t  bf16 (64x64)         w2t[col*64+k]
//   [139264,4333568) featT bf16 (32*4096*16)   featT[((c*4096+src)*16)+b]
#define WS_W3T_OFF    0
#define WS_W2T_OFF    131072
#define WS_FEATT_OFF  139264
#define WS_NEED       4333568

__global__ void qc_zero_kernel(float* __restrict__ out, int n4) {
    int i = blockIdx.x * blockDim.x + threadIdx.x;
    if (i < n4) ((float4*)out)[i] = make_float4(0.f, 0.f, 0.f, 0.f);
}

// Fallback prep: w3t/w2t only
__global__ void qc_prep_kernel(const float* __restrict__ w3, const float* __restrict__ w2,
                               __bf16* __restrict__ w3t, __bf16* __restrict__ w2t) {
    int gid = blockIdx.x * blockDim.x + threadIdx.x;
    if (gid < 65536) {
        int k = gid & 63, col = gid >> 6;
        w3t[gid] = (__bf16)w3[k * 1024 + col];
    } else {
        int j = gid - 65536;
        int k = j & 63, col = j >> 6;
        w2t[j] = (__bf16)w2[k * 64 + col];
    }
}

// Fused prep: zero out (512 blks) + w3t (256) + w2t (16) + featT transpose (512)
__global__ void qc_prep2_kernel(const float* __restrict__ w3, const float* __restrict__ w2,
                                const float* __restrict__ feat,
                                float* __restrict__ out,
                                __bf16* __restrict__ w3t, __bf16* __restrict__ w2t,
                                __bf16* __restrict__ featT) {
    int bid = blockIdx.x, tid = threadIdx.x;
    if (bid < 512) {
        int i = bid * 256 + tid;                     // 131072 float4s
        ((float4*)out)[i] = make_float4(0.f, 0.f, 0.f, 0.f);
    } else if (bid < 768) {
        int gid = (bid - 512) * 256 + tid;           // 65536
        int k = gid & 63, col = gid >> 6;
        w3t[gid] = (__bf16)w3[k * 1024 + col];
    } else if (bid < 784) {
        int j = (bid - 768) * 256 + tid;             // 4096
        int k = j & 63, col = j >> 6;
        w2t[j] = (__bf16)w2[k * 64 + col];
    } else {
        // featT[c][src][b] = feat[b][c][src]; 512 blocks cover 32 c x 16 chunks
        int bid2 = bid - 784;                        // 0..511
        int c    = bid2 >> 4;                        // 0..31
        int src  = (bid2 & 15) * 256 + tid;          // 0..4095
        bf16x16 v;
        #pragma unroll
        for (int b = 0; b < 16; ++b)                 // coalesced dword loads per b
            v[b] = (__bf16)feat[(b * 32 + c) * N_IN + src];
        __bf16* p = &featT[((size_t)c * N_IN + src) * 16];   // 32B/thread, coalesced
        *(bf16x8*)p       = *(bf16x8*)&v;
        *(bf16x8*)(p + 8) = *((bf16x8*)&v + 1);
    }
}

// ---------------------------------------------------------------------------
// Fused kernel: 512 threads per 16-row tile.
//   [issue 1x32B featT gather/thread] + idx/h1 -> S1 -> h2 (MFMA) -> S2 ->
//   filt (MFMA -> LDS) -> park gather (LDS transpose) -> S3 ->
//   einsum (MFMA) -> vals -> run-merged atomic scatter.
// ---------------------------------------------------------------------------
__global__ __launch_bounds__(512, 4)
void qc_fused_kernel(const __bf16* __restrict__ featT,
                     const float* __restrict__ w1,
                     const float* __restrict__ locs,
                     const int*   __restrict__ eidx,
                     const __bf16* __restrict__ w2t,
                     const __bf16* __restrict__ w3t,
                     float* __restrict__ out,
                     int E)
{
    __shared__ __align__(16) __bf16 h1b[ROWS * H1_STR];   // 2304 B
    __shared__ __align__(16) __bf16 h2b[ROWS * H2_STR];   // 2304 B
    __shared__ __align__(16) __bf16 ftv[ROWS * FT_NSTR];  // 40960 B
    __shared__ __align__(16) __bf16 gb [BATCH * G_STR];   // 16640 B (later: vals)
    __shared__ unsigned short seg_s[512];                 // 1024 B
    // total 63232 B -> 2 blocks/CU

    const int tid = threadIdx.x;
    const int n0  = blockIdx.x * ROWS;
    const int t0  = n0 * 32;
    const int ch0 = t0 / E;
    const int m0  = t0 - ch0 * E;          // block spans <512 t's -> at most one wrap

    // ---- Gather: ONE 32B load per thread (all 16 batches), issued first ----
    int mm = m0 + tid;
    const int cc = ch0 + (mm >= E);
    if (mm >= E) mm -= E;
    int2 p = ((const int2*)eidx)[mm];      // .x = seg, .y = src
    bf16x16 gv = {};
    if (cc < 32)
        gv = *(const bf16x16*)&featT[((size_t)cc * N_IN + p.y) * 16];
    seg_s[tid] = (unsigned short)p.x;

    // ---- Phase A: h1 = sin(loc @ W1) ----
    {
        const int r  = tid >> 5;
        const int j0 = (tid & 31) * 2;
        float lx = 0.f, ly = 0.f;
        int n = n0 + r;
        if (n < E) { lx = locs[n * 2]; ly = locs[n * 2 + 1]; }
        float2 wa = *(const float2*)&w1[j0];
        float2 wb = *(const float2*)&w1[64 + j0];
        __bf16* h = &h1b[r * H1_STR + j0];
        h[0] = (__bf16)__sinf(lx * wa.x + ly * wb.x);
        h[1] = (__bf16)__sinf(lx * wa.y + ly * wb.y);
    }
    __syncthreads();   // S1

    const int lane = tid & 63;
    const int wv   = tid >> 6;      // 0..7
    const int ml   = lane & 15;
    const int q    = lane >> 4;

    // ---- Phase B: h2 = sin(h1 @ W2) via MFMA (waves 0..3, 16 cols each) ----
    if (wv < 4) {
        bf16x8 a0 = *(const bf16x8*)&h1b[ml * H1_STR + q * 8];
        bf16x8 a1 = *(const bf16x8*)&h1b[ml * H1_STR + 32 + q * 8];
        const __bf16* wp = &w2t[(wv * 16 + ml) * 64 + q * 8];
        bf16x8 b0 = *(const bf16x8*)wp;
        bf16x8 b1 = *(const bf16x8*)(wp + 32);
        f32x4 c = {0.f, 0.f, 0.f, 0.f};
        c = __builtin_amdgcn_mfma_f32_16x16x32_bf16(a0, b0, c, 0, 0, 0);
        c = __builtin_amdgcn_mfma_f32_16x16x32_bf16(a1, b1, c, 0, 0, 0);
        #pragma unroll
        for (int g_ = 0; g_ < 4; ++g_)
            h2b[(q * 4 + g_) * H2_STR + wv * 16 + ml] = (__bf16)__sinf(c[g_]);
    }
    __syncthreads();   // S2

    // ---- Phase C: filt = h2 @ W3 via MFMA; filtT[n][j][i] into LDS ----
    {
        bf16x8 a0 = *(const bf16x8*)&h2b[ml * H2_STR + q * 8];
        bf16x8 a1 = *(const bf16x8*)&h2b[ml * H2_STR + 32 + q * 8];
        #pragma unroll
        for (int t = 0; t < 8; ++t) {
            int col = wv * 128 + t * 16 + ml;          // = i*32 + j
            const __bf16* wp = &w3t[col * 64 + q * 8];
            bf16x8 b0 = *(const bf16x8*)wp;
            bf16x8 b1 = *(const bf16x8*)(wp + 32);
            f32x4 c = {0.f, 0.f, 0.f, 0.f};
            c = __builtin_amdgcn_mfma_f32_16x16x32_bf16(a0, b0, c, 0, 0, 0);
            c = __builtin_amdgcn_mfma_f32_16x16x32_bf16(a1, b1, c, 0, 0, 0);
            int i_ = col >> 5, j_ = col & 31;
            __bf16* fp = &ftv[j_ * FT_JSTR + i_];
            fp[(q * 4 + 0) * FT_NSTR] = (__bf16)c[0];
            fp[(q * 4 + 1) * FT_NSTR] = (__bf16)c[1];
            fp[(q * 4 + 2) * FT_NSTR] = (__bf16)c[2];
            fp[(q * 4 + 3) * FT_NSTR] = (__bf16)c[3];
        }
    }
    // ---- Park gathered batches into gb (LDS transpose; stride-1 writes) ----
    #pragma unroll
    for (int b = 0; b < 16; ++b)
        gb[b * G_STR + tid] = gv[b];
    __syncthreads();   // S3

    // ---- Phase D: vals[b][j] = g[b][:] @ filt[r]; 8 waves x 2 rows ----
    {
        bf16x8 ag[2], f0[2], f1[2];
        #pragma unroll
        for (int rr = 0; rr < 2; ++rr) {
            int r = wv * 2 + rr;
            f0[rr] = *(const bf16x8*)&ftv[r * FT_NSTR + ml        * FT_JSTR + q * 8];
            f1[rr] = *(const bf16x8*)&ftv[r * FT_NSTR + (16 + ml) * FT_JSTR + q * 8];
            ag[rr] = *(const bf16x8*)&gb[ml * G_STR + r * 32 + q * 8];
        }
        f32x4 c0[2], c1[2];
        #pragma unroll
        for (int rr = 0; rr < 2; ++rr) {
            f32x4 z = {0.f, 0.f, 0.f, 0.f};
            c0[rr] = __builtin_amdgcn_mfma_f32_16x16x32_bf16(ag[rr], f0[rr], z, 0, 0, 0);
            c1[rr] = __builtin_amdgcn_mfma_f32_16x16x32_bf16(ag[rr], f1[rr], z, 0, 0, 0);
        }
        __syncthreads();   // S4a: gb reads done; overlay vals onto gb
        __bf16* valsb = gb;
        #pragma unroll
        for (int rr = 0; rr < 2; ++rr) {
            int r = wv * 2 + rr;
            __bf16* vp = &valsb[r * 32];
            #pragma unroll
            for (int g_ = 0; g_ < 4; ++g_) {
                int b = q * 4 + g_;
                vp[b * V_STR + ml]      = (__bf16)c0[rr][g_];
                vp[b * V_STR + 16 + ml] = (__bf16)c1[rr][g_];
            }
        }
    }
    __syncthreads();   // S4b

    // ---- Phase E: run-merged atomic scatter (512 thr x 16 vals) ----
    {
        const __bf16* valsb = gb;
        const int b    = tid >> 5;            // 0..15
        const int rem  = tid & 31;
        const int tl0  = (rem >> 1) * 32 + (rem & 1) * 16;
        const __bf16* vp = &valsb[b * V_STR + tl0];
        bf16x8 v0 = *(const bf16x8*)(vp);
        bf16x8 v1 = *(const bf16x8*)(vp + 8);
        float vv[16];
        #pragma unroll
        for (int j = 0; j < 8; ++j) { vv[j] = (float)v0[j]; vv[8 + j] = (float)v1[j]; }
        int key_prev = -1;
        float acc = 0.f;
        #pragma unroll
        for (int j = 0; j < 16; ++j) {
            int mm2 = m0 + tl0 + j;
            int cc2 = ch0 + (mm2 >= E);
            if (mm2 >= E) mm2 -= E;
            if (cc2 < 32) {
                int o   = (int)seg_s[tl0 + j];
                int key = ((b * 32 + cc2) << 10) | o;
                if (key != key_prev) {
                    if (key_prev >= 0) atomicAdd(&out[key_prev], acc);
                    key_prev = key;
                    acc = vv[j];
                } else {
                    acc += vv[j];
                }
            }
        }
        if (key_prev >= 0) atomicAdd(&out[key_prev], acc);
    }
}

// ---------------------------------------------------------------------------
// Fallback: round-1 fused kernel (used only if ws too small)
// ---------------------------------------------------------------------------
#define FB_FT_NSTR 1288
__global__ __launch_bounds__(256, 2)
void qc_main_kernel(const float* __restrict__ feat,
                    const float* __restrict__ w1,
                    const float* __restrict__ w2,
                    const float* __restrict__ locs,
                    const int*   __restrict__ eidx,
                    const __bf16* __restrict__ w3t,
                    float* __restrict__ out,
                    int E)
{
    __shared__ __align__(16) __bf16 h1b[ROWS * H1_STR];
    __shared__ __align__(16) __bf16 h2b[ROWS * H2_STR];
    __shared__ __align__(16) __bf16 ftv[ROWS * FB_FT_NSTR];
    __shared__ __align__(16) __bf16 gb [BATCH * G_STR];
    __shared__ unsigned short seg_s[512];
    __shared__ unsigned short src_s[512];

    const int tid = threadIdx.x;
    const int n0  = blockIdx.x * ROWS;
    const int t0  = n0 * 32;
    const int ch0 = t0 / E;
    const int m0  = t0 - ch0 * E;

    {
        const int r  = tid >> 4;
        const int j0 = (tid & 15) * 4;
        float lx = 0.f, ly = 0.f;
        int n = n0 + r;
        if (n < E) { lx = locs[n * 2]; ly = locs[n * 2 + 1]; }
        float4 wa = *(const float4*)&w1[j0];
        float4 wb = *(const float4*)&w1[64 + j0];
        __bf16* h = &h1b[r * H1_STR + j0];
        h[0] = (__bf16)__sinf(lx * wa.x + ly * wb.x);
        h[1] = (__bf16)__sinf(lx * wa.y + ly * wb.y);
        h[2] = (__bf16)__sinf(lx * wa.z + ly * wb.z);
        h[3] = (__bf16)__sinf(lx * wa.w + ly * wb.w);
    }
    for (int tl = tid; tl < 512; tl += 256) {
        int mm = m0 + tl; if (mm >= E) mm -= E;
        seg_s[tl] = (unsigned short)eidx[mm * 2];
        src_s[tl] = (unsigned short)eidx[mm * 2 + 1];
    }
    __syncthreads();

    {
        const int r  = tid >> 4;
        const int j0 = (tid & 15) * 4;
        float a0 = 0.f, a1 = 0.f, a2 = 0.f, a3 = 0.f;
        const __bf16* h1r = &h1b[r * H1_STR];
        #pragma unroll 8
        for (int k = 0; k < 64; ++k) {
            float h = (float)h1r[k];
            float4 w = *(const float4*)&w2[k * 64 + j0];
            a0 += h * w.x; a1 += h * w.y; a2 += h * w.z; a3 += h * w.w;
        }
        __bf16* h = &h2b[r * H2_STR + j0];
        h[0] = (__bf16)__sinf(a0);
        h[1] = (__bf16)__sinf(a1);
        h[2] = (__bf16)__sinf(a2);
        h[3] = (__bf16)__sinf(a3);
    }
    #pragma unroll 4
    for (int it = 0; it < 32; ++it) {
        int idx = it * 256 + tid;
        int b   = idx >> 9;
        int tl  = idx & 511;
        int mm  = m0 + tl;
        int cc  = ch0 + (mm >= E);
        if (mm >= E) mm -= E;
        float v = 0.f;
        if (cc < 32) v = feat[(b * 32 + cc) * N_IN + (int)src_s[tl]];
        gb[b * G_STR + tl] = (__bf16)v;
    }
    __syncthreads();

    const int lane = tid & 63;
    const int wv   = tid >> 6;
    const int ml   = lane & 15;
    const int q    = lane >> 4;

    {
        bf16x8 a0 = *(const bf16x8*)&h2b[ml * H2_STR + q * 8];
        bf16x8 a1 = *(const bf16x8*)&h2b[ml * H2_STR + 32 + q * 8];
        #pragma unroll
        for (int t = 0; t < 16; ++t) {
            int col = wv * 256 + t * 16 + ml;
            const __bf16* wp = &w3t[col * 64 + q * 8];
            bf16x8 b0 = *(const bf16x8*)wp;
            bf16x8 b1 = *(const bf16x8*)(wp + 32);
            f32x4 c = {0.f, 0.f, 0.f, 0.f};
            c = __builtin_amdgcn_mfma_f32_16x16x32_bf16(a0, b0, c, 0, 0, 0);
            c = __builtin_amdgcn_mfma_f32_16x16x32_bf16(a1, b1, c, 0, 0, 0);
            int i_ = col >> 5, j_ = col & 31;
            __bf16* fp = &ftv[j_ * FT_JSTR + i_];
            fp[(q * 4 + 0) * FB_FT_NSTR] = (__bf16)c[0];
            fp[(q * 4 + 1) * FB_FT_NSTR] = (__bf16)c[1];
            fp[(q * 4 + 2) * FB_FT_NSTR] = (__bf16)c[2];
            fp[(q * 4 + 3) * FB_FT_NSTR] = (__bf16)c[3];
        }
    }
    __syncthreads();

    {
        bf16x8 ag[4], f0[4], f1[4];
        #pragma unroll
        for (int rr = 0; rr < 4; ++rr) {
            int r = wv * 4 + rr;
            ag[rr] = *(const bf16x8*)&gb[ml * G_STR + r * 32 + q * 8];
            f0[rr] = *(const bf16x8*)&ftv[r * FB_FT_NSTR + ml        * FT_JSTR + q * 8];
            f1[rr] = *(const bf16x8*)&ftv[r * FB_FT_NSTR + (16 + ml) * FT_JSTR + q * 8];
        }
        __syncthreads();
        __bf16* valsb = ftv;
        #pragma unroll
        for (int rr = 0; rr < 4; ++rr) {
            int r = wv * 4 + rr;
            f32x4 c0 = {0.f, 0.f, 0.f, 0.f};
            f32x4 c1 = {0.f, 0.f, 0.f, 0.f};
            c0 = __builtin_amdgcn_mfma_f32_16x16x32_bf16(ag[rr], f0[rr], c0, 0, 0, 0);
            c1 = __builtin_amdgcn_mfma_f32_16x16x32_bf16(ag[rr], f1[rr], c1, 0, 0, 0);
            __bf16* vp = &valsb[r * 32];
            #pragma unroll
            for (int g_ = 0; g_ < 4; ++g_) {
                int b = q * 4 + g_;
                vp[b * V_STR + ml]      = (__bf16)c0[g_];
                vp[b * V_STR + 16 + ml] = (__bf16)c1[g_];
            }
        }
    }
    __syncthreads();

    {
        const __bf16* valsb = ftv;
        const int b = tid >> 4;
        const int r = tid & 15;
        const __bf16* vp = &valsb[b * V_STR + r * 32];
        bf16x8 v0 = *(const bf16x8*)(vp);
        bf16x8 v1 = *(const bf16x8*)(vp + 8);
        bf16x8 v2 = *(const bf16x8*)(vp + 16);
        bf16x8 v3 = *(const bf16x8*)(vp + 24);
        float vv[32];
        #pragma unroll
        for (int j = 0; j < 8; ++j) {
            vv[j]      = (float)v0[j];
            vv[8 + j]  = (float)v1[j];
            vv[16 + j] = (float)v2[j];
            vv[24 + j] = (float)v3[j];
        }
        const int tl0 = r * 32;
        int key_prev = -1;
        float acc = 0.f;
        #pragma unroll
        for (int j = 0; j < 32; ++j) {
            int mm = m0 + tl0 + j;
            int cc = ch0 + (mm >= E);
            if (mm >= E) mm -= E;
            if (cc < 32) {
                int o   = (int)seg_s[tl0 + j];
                int key = ((b * 32 + cc) << 10) | o;
                if (key != key_prev) {
                    if (key_prev >= 0) atomicAdd(&out[key_prev], acc);
                    key_prev = key;
                    acc = vv[j];
                } else {
                    acc += vv[j];
                }
            }
        }
        if (key_prev >= 0) atomicAdd(&out[key_prev], acc);
    }
}

extern "C" void kernel_launch(void* const* d_in, const int* in_sizes, int n_in,
                              void* d_out, int out_size, void* d_ws, size_t ws_size,
                              hipStream_t stream)
{
    (void)n_in;
    const float* feat = (const float*)d_in[0];
    const float* w1   = (const float*)d_in[1];
    const float* w2   = (const float*)d_in[2];
    const float* w3   = (const float*)d_in[3];
    const float* locs = (const float*)d_in[4];
    const int*   eidx = (const int*)d_in[5];
    float* out  = (float*)d_out;

    const int E = in_sizes[4] / 2;
    if (E <= 0) return;

    __bf16* w3t   = (__bf16*)((char*)d_ws + WS_W3T_OFF);
    __bf16* w2t   = (__bf16*)((char*)d_ws + WS_W2T_OFF);
    __bf16* featT = (__bf16*)((char*)d_ws + WS_FEATT_OFF);

    int nblocks = (E + ROWS - 1) / ROWS;

    if (ws_size >= (size_t)WS_NEED) {
        qc_prep2_kernel<<<1296, 256, 0, stream>>>(w3, w2, feat, out, w3t, w2t, featT);
        qc_fused_kernel<<<nblocks, 512, 0, stream>>>(featT, w1, locs, eidx, w2t, w3t, out, E);
    } else {
        int n4 = out_size / 4;
        qc_zero_kernel<<<(n4 + 255) / 256, 256, 0, stream>>>(out, n4);
        qc_prep_kernel<<<272, 256, 0, stream>>>(w3, w2, w3t, w2t);
        qc_main_kernel<<<nblocks, 256, 0, stream>>>(feat, w1, w2, locs, eidx, w3t, out, E);
    }
}